// Round 8
// baseline (646.593 us; speedup 1.0000x reference)
//
#include <hip/hip_runtime.h>
#include <math.h>

#define NG 64          // graphs
#define F_IN 128
#define NEG_SLOPE 0.2f

typedef __attribute__((ext_vector_type(8))) short s16x8;
typedef __attribute__((ext_vector_type(4))) float f32x4;

// ---------- helpers ----------
static __device__ __forceinline__ float elu_f(float x) { return x > 0.f ? x : expm1f(x); }
static __device__ __forceinline__ float lrelu(float x) { return x > 0.f ? x : NEG_SLOPE * x; }
static __device__ __forceinline__ unsigned enc_f32(float x) {
    unsigned u = __float_as_uint(x);
    return (u & 0x80000000u) ? ~u : (u | 0x80000000u);
}
static __device__ __forceinline__ float dec_f32(unsigned u) {
    unsigned b = (u & 0x80000000u) ? (u & 0x7fffffffu) : ~u;
    return __uint_as_float(b);
}
static __device__ __forceinline__ unsigned short bf16_rn(float x) {
    unsigned u = __float_as_uint(x);
    unsigned r = u + 0x7FFFu + ((u >> 16) & 1u);
    return (unsigned short)(r >> 16);
}
static __device__ __forceinline__ float bf16_to_f32(unsigned short h) {
    return __uint_as_float(((unsigned)h) << 16);
}
static __device__ __forceinline__ unsigned pack_split(float x) {
    unsigned short hi = bf16_rn(x);
    unsigned short lo = bf16_rn(x - bf16_to_f32(hi));
    return ((unsigned)hi << 16) | lo;
}

// ---------- pre-pack kernels ----------
// f32 -> packed (hi<<16|lo) uint
__global__ void convert_pack(const float* __restrict__ in, unsigned* __restrict__ out, int n) {
    int idx = (blockIdx.x * blockDim.x + threadIdx.x) * 4;
    if (idx + 3 < n) {
        float4 v = *(const float4*)&in[idx];
        uint4 o;
        o.x = pack_split(v.x); o.y = pack_split(v.y);
        o.z = pack_split(v.z); o.w = pack_split(v.w);
        *(uint4*)&out[idx] = o;
    }
}

// f32 -> separate hi / lo bf16 arrays (for W operands: direct s16x8 fragment loads)
__global__ void convert_dual(const float* __restrict__ in, unsigned short* __restrict__ hi,
                             unsigned short* __restrict__ lo, int n) {
    int idx = (blockIdx.x * blockDim.x + threadIdx.x) * 4;
    if (idx + 3 < n) {
        float4 v = *(const float4*)&in[idx];
        ushort4 h, l;
        h.x = bf16_rn(v.x); l.x = bf16_rn(v.x - bf16_to_f32(h.x));
        h.y = bf16_rn(v.y); l.y = bf16_rn(v.y - bf16_to_f32(h.y));
        h.z = bf16_rn(v.z); l.z = bf16_rn(v.z - bf16_to_f32(h.z));
        h.w = bf16_rn(v.w); l.w = bf16_rn(v.w - bf16_to_f32(h.w));
        *(ushort4*)&hi[idx] = h;
        *(ushort4*)&lo[idx] = l;
    }
}

// u[h][i] = sum_o W1[h*64+o][i] * a[h][o]   (layer-1 commute attention scalars)
__global__ void uvec_kernel(const float* __restrict__ W1, const float* __restrict__ a1s,
                            const float* __restrict__ a1d,
                            float* __restrict__ us, float* __restrict__ ud) {
    int h = threadIdx.x >> 6;
    int i = threadIdx.x & 63;
    float s = 0.f, d = 0.f;
    for (int o = 0; o < 64; ++o) {
        float w = W1[(h * 64 + o) * 64 + i];
        s = fmaf(w, a1s[h * 64 + o], s);
        d = fmaf(w, a1d[h * 64 + o], d);
    }
    us[h * 64 + i] = s;
    ud[h * 64 + i] = d;
}

// ---------- CSR build ----------
__global__ void hist_kernel(const int* __restrict__ ei, int* __restrict__ cnt, int E, int N) {
    int e = blockIdx.x * blockDim.x + threadIdx.x;
    int ET = E + N;
    if (e >= ET) return;
    int dst = (e < E) ? ei[E + e] : (e - E);
    atomicAdd(&cnt[dst], 1);
}

__global__ void scan1_kernel(const int* __restrict__ cnt, int* __restrict__ excl,
                             int* __restrict__ bsum, int n) {
    __shared__ int sm[256];
    int t = threadIdx.x;
    int base = blockIdx.x * 1024 + t * 4;
    int v[4];
    #pragma unroll
    for (int u = 0; u < 4; ++u) { int idx = base + u; v[u] = (idx < n) ? cnt[idx] : 0; }
    int tsum = v[0] + v[1] + v[2] + v[3];
    sm[t] = tsum;
    __syncthreads();
    for (int off = 1; off < 256; off <<= 1) {
        int y = (t >= off) ? sm[t - off] : 0;
        __syncthreads();
        sm[t] += y;
        __syncthreads();
    }
    int run = sm[t] - tsum;
    #pragma unroll
    for (int u = 0; u < 4; ++u) {
        int idx = base + u;
        if (idx < n) excl[idx] = run;
        run += v[u];
    }
    if (t == 255) bsum[blockIdx.x] = sm[255];
}

__global__ void scan2_kernel(int* __restrict__ bsum, int* __restrict__ offs, int nb, int n) {
    if (blockIdx.x == 0 && threadIdx.x == 0) {
        int run = 0;
        for (int b = 0; b < nb; ++b) { int t = bsum[b]; bsum[b] = run; run += t; }
        offs[n] = run;
    }
}

__global__ void scan3_kernel(int* __restrict__ offs, const int* __restrict__ bsum, int n) {
    int base = blockIdx.x * 1024 + threadIdx.x * 4;
    int add = bsum[blockIdx.x];
    #pragma unroll
    for (int u = 0; u < 4; ++u) { int idx = base + u; if (idx < n) offs[idx] += add; }
}

__global__ void scatter_kernel(const int* __restrict__ ei, const int* __restrict__ offs,
                               int* __restrict__ cursor, int* __restrict__ csr_src, int E, int N) {
    int e = blockIdx.x * blockDim.x + threadIdx.x;
    int ET = E + N;
    if (e >= ET) return;
    int src, dst;
    if (e < E) { src = ei[e]; dst = ei[E + e]; }
    else       { src = e - E; dst = e - E; }
    int pos = offs[dst] + atomicAdd(&cursor[dst], 1);
    csr_src[pos] = src;
}

// ---------- LDS-free split-bf16 MFMA GEMM ----------
// A: packed-split uint [N][lda]; W: pre-split Whi/Wlo ushort [M][K].
// Out[n][m] = dot(A[n][aoff:aoff+K], Wrow[m]) (+bias) (elu opt)
// BN=256: 4 waves each own 64 rows x 64 cols (RF=4, CF=4; wave w = head w for HATT).
// BN=64:  4 waves each own 16 rows x 64 cols (RF=1, CF=4).
// OUTM: 0=f32, 1=bf16 ushort, 2=packed-split uint.
template<int K, int BN, int HATT, bool SHARED, bool SLICED, bool DO_ELU, int OUTM>
__global__ __launch_bounds__(256) void gemm_nolds(const unsigned* __restrict__ Ap, int lda,
                                                  const unsigned short* __restrict__ Whi,
                                                  const unsigned short* __restrict__ Wlo,
                                                  void* __restrict__ OutV, int M,
                                                  const float* __restrict__ bias,
                                                  const float* __restrict__ asrc,
                                                  const float* __restrict__ adst,
                                                  float* __restrict__ S, float* __restrict__ D,
                                                  int N) {
    constexpr int RF = (BN == 256) ? 4 : 1;
    constexpr int CF = 4;
    const int t = threadIdx.x;
    const int lane = t & 63;
    const int w = t >> 6;
    const int lj = lane & 15;
    const int kg = lane >> 4;
    const int n0 = blockIdx.x * 64;
    const int m0 = blockIdx.y * BN;
    const int rbase = (BN == 256) ? 0 : w * 16;
    const int cbase = (BN == 256) ? w * 64 : 0;
    const int aoff = SLICED ? blockIdx.y * K : 0;
    const unsigned short* __restrict__ WhiB = SLICED ? Whi + (size_t)blockIdx.y * BN * K : Whi;
    const unsigned short* __restrict__ WloB = SLICED ? Wlo + (size_t)blockIdx.y * BN * K : Wlo;

    f32x4 acc[RF][CF];
    #pragma unroll
    for (int rf = 0; rf < RF; ++rf)
        #pragma unroll
        for (int cf = 0; cf < CF; ++cf) acc[rf][cf] = (f32x4){0.f, 0.f, 0.f, 0.f};

    for (int kc = 0; kc < K; kc += 32) {
        // A fragments: packed -> hi/lo s16x8 (2 shifts per elem)
        s16x8 ah[RF], al[RF];
        #pragma unroll
        for (int rf = 0; rf < RF; ++rf) {
            int row = n0 + rbase + rf * 16 + lj;
            unsigned p[8];
            if (row < N) {
                uint4 q0 = *(const uint4*)&Ap[(size_t)row * lda + aoff + kc + kg * 8];
                uint4 q1 = *(const uint4*)&Ap[(size_t)row * lda + aoff + kc + kg * 8 + 4];
                p[0] = q0.x; p[1] = q0.y; p[2] = q0.z; p[3] = q0.w;
                p[4] = q1.x; p[5] = q1.y; p[6] = q1.z; p[7] = q1.w;
            } else {
                #pragma unroll
                for (int i = 0; i < 8; ++i) p[i] = 0;
            }
            #pragma unroll
            for (int i = 0; i < 8; ++i) {
                ah[rf][i] = (short)(p[i] >> 16);
                al[rf][i] = (short)(p[i] & 0xffffu);
            }
        }
        // B fragments: direct s16x8 loads from L2-resident pre-split W
        #pragma unroll
        for (int cf = 0; cf < CF; ++cf) {
            int wcol = (SLICED ? 0 : m0) + cbase + cf * 16 + lj;
            s16x8 bh = *(const s16x8*)&WhiB[(size_t)wcol * K + kc + kg * 8];
            s16x8 bl = *(const s16x8*)&WloB[(size_t)wcol * K + kc + kg * 8];
            #pragma unroll
            for (int rf = 0; rf < RF; ++rf) {
                acc[rf][cf] = __builtin_amdgcn_mfma_f32_16x16x32_bf16(ah[rf], bh, acc[rf][cf], 0, 0, 0);
                acc[rf][cf] = __builtin_amdgcn_mfma_f32_16x16x32_bf16(ah[rf], bl, acc[rf][cf], 0, 0, 0);
                acc[rf][cf] = __builtin_amdgcn_mfma_f32_16x16x32_bf16(al[rf], bh, acc[rf][cf], 0, 0, 0);
            }
        }
    }

    // epilogue: C/D layout col=lane&15, row=(lane>>4)*4+reg
    #pragma unroll
    for (int cf = 0; cf < CF; ++cf) {
        int gcol = m0 + cbase + cf * 16 + lj;
        float bv = bias ? bias[gcol] : 0.f;
        #pragma unroll
        for (int rf = 0; rf < RF; ++rf) {
            #pragma unroll
            for (int r = 0; r < 4; ++r) {
                int gn = n0 + rbase + rf * 16 + (lane >> 4) * 4 + r;
                if (gn < N) {
                    float o = acc[rf][cf][r] + bv;
                    if (DO_ELU) o = elu_f(o);
                    if (OUTM == 0)      ((float*)OutV)[(size_t)gn * M + gcol] = o;
                    else if (OUTM == 1) ((unsigned short*)OutV)[(size_t)gn * M + gcol] = bf16_rn(o);
                    else                ((unsigned*)OutV)[(size_t)gn * M + gcol] = pack_split(o);
                }
            }
        }
    }
    // fused attention scalars (f32 acc, post-bias)
    if (HATT > 0) {
        if (BN == 256) {
            // wave w owns head w's 64 cols
            float aw[CF], dw[CF], bw[CF];
            #pragma unroll
            for (int cf = 0; cf < CF; ++cf) {
                aw[cf] = asrc[w * 64 + cf * 16 + lj];
                dw[cf] = adst[w * 64 + cf * 16 + lj];
                bw[cf] = bias ? bias[m0 + cbase + cf * 16 + lj] : 0.f;
            }
            #pragma unroll
            for (int rf = 0; rf < RF; ++rf) {
                #pragma unroll
                for (int r = 0; r < 4; ++r) {
                    float sp = 0.f, dp = 0.f;
                    #pragma unroll
                    for (int cf = 0; cf < CF; ++cf) {
                        float vv = acc[rf][cf][r] + bw[cf];
                        sp = fmaf(vv, aw[cf], sp);
                        dp = fmaf(vv, dw[cf], dp);
                    }
                    #pragma unroll
                    for (int off = 1; off < 16; off <<= 1) {
                        sp += __shfl_xor(sp, off);
                        dp += __shfl_xor(dp, off);
                    }
                    if (lj == 0) {
                        int gn = n0 + rf * 16 + (lane >> 4) * 4 + r;
                        if (gn < N) { S[gn * HATT + w] = sp; D[gn * HATT + w] = dp; }
                    }
                }
            }
        } else {
            // SHARED: HATT heads over the same 64 cols (RF=1)
            #pragma unroll
            for (int hh = 0; hh < HATT; ++hh) {
                float aw[CF], dw[CF], bw[CF];
                #pragma unroll
                for (int c2 = 0; c2 < CF; ++c2) {
                    aw[c2] = asrc[hh * 64 + c2 * 16 + lj];
                    dw[c2] = adst[hh * 64 + c2 * 16 + lj];
                    bw[c2] = bias ? bias[m0 + c2 * 16 + lj] : 0.f;
                }
                #pragma unroll
                for (int r = 0; r < 4; ++r) {
                    float sp = 0.f, dp = 0.f;
                    #pragma unroll
                    for (int c2 = 0; c2 < CF; ++c2) {
                        float vv = acc[0][c2][r] + bw[c2];
                        sp = fmaf(vv, aw[c2], sp);
                        dp = fmaf(vv, dw[c2], dp);
                    }
                    #pragma unroll
                    for (int off = 1; off < 16; off <<= 1) {
                        sp += __shfl_xor(sp, off);
                        dp += __shfl_xor(dp, off);
                    }
                    if (lj == 0) {
                        int gn = n0 + w * 16 + (lane >> 4) * 4 + r;
                        if (gn < N) { S[gn * HATT + hh] = sp; D[gn * HATT + hh] = dp; }
                    }
                }
            }
        }
    }
}

// ---------- layer-1 aggregation over raw emb (commuted); output packed-split ----------
__global__ __launch_bounds__(256, 8) void gat_agg_x(const float* __restrict__ xA,  // [N][64] f32
                                                    const float* __restrict__ s,   // [N][4]
                                                    const float* __restrict__ d,
                                                    const int* __restrict__ offs,
                                                    const int* __restrict__ csr_src,
                                                    unsigned* __restrict__ G,      // [N][4][64] packed
                                                    int N) {
    __shared__ float stash[4][64 * 5];
    int wv = threadIdx.x >> 6;
    int lane = threadIdx.x & 63;
    int node = (blockIdx.x * blockDim.x + threadIdx.x) >> 6;
    if (node >= N) return;
    float* st = stash[wv];
    int e0 = offs[node], e1 = offs[node + 1];
    float4 dv4 = *(const float4*)&d[node * 4];
    float dd[4] = {dv4.x, dv4.y, dv4.z, dv4.w};
    float mrun[4] = {-INFINITY, -INFINITY, -INFINITY, -INFINITY};
    float den[4] = {0.f, 0.f, 0.f, 0.f};
    float acc[4] = {0.f, 0.f, 0.f, 0.f};

    for (int base = e0; base < e1; base += 64) {
        int cnt = min(64, e1 - base);
        float ev[4] = {-INFINITY, -INFINITY, -INFINITY, -INFINITY};
        if (lane < cnt) {
            int src = csr_src[base + lane];
            float4 sv = *(const float4*)&s[src * 4];
            ev[0] = lrelu(sv.x + dd[0]); ev[1] = lrelu(sv.y + dd[1]);
            ev[2] = lrelu(sv.z + dd[2]); ev[3] = lrelu(sv.w + dd[3]);
            st[lane * 5 + 0] = ev[0]; st[lane * 5 + 1] = ev[1];
            st[lane * 5 + 2] = ev[2]; st[lane * 5 + 3] = ev[3];
            st[lane * 5 + 4] = __int_as_float(src);
        }
        #pragma unroll
        for (int h = 0; h < 4; ++h) {
            float m = ev[h];
            #pragma unroll
            for (int off = 32; off; off >>= 1) m = fmaxf(m, __shfl_xor(m, off));
            float mnew = fmaxf(mrun[h], m);
            float scale = __expf(mrun[h] - mnew);
            acc[h] *= scale; den[h] *= scale;
            mrun[h] = mnew;
        }
        int k = 0;
        for (; k + 4 <= cnt; k += 4) {
            int si[4];
            #pragma unroll
            for (int u = 0; u < 4; ++u) si[u] = __float_as_int(st[(k + u) * 5 + 4]);
            float vx[4];
            #pragma unroll
            for (int u = 0; u < 4; ++u) vx[u] = xA[(size_t)si[u] * 64 + lane];
            #pragma unroll
            for (int u = 0; u < 4; ++u) {
                #pragma unroll
                for (int h = 0; h < 4; ++h) {
                    float p = __expf(st[(k + u) * 5 + h] - mrun[h]);
                    den[h] += p;
                    acc[h] = fmaf(p, vx[u], acc[h]);
                }
            }
        }
        for (; k < cnt; ++k) {
            int src = __float_as_int(st[k * 5 + 4]);
            float v = xA[(size_t)src * 64 + lane];
            #pragma unroll
            for (int h = 0; h < 4; ++h) {
                float p = __expf(st[k * 5 + h] - mrun[h]);
                den[h] += p;
                acc[h] = fmaf(p, v, acc[h]);
            }
        }
    }
    #pragma unroll
    for (int h = 0; h < 4; ++h)
        G[(size_t)node * 256 + h * 64 + lane] = pack_split(acc[h] / (den[h] + 1e-16f));
}

// ---------- GAT aggregation: one wave per dst node, chunked online softmax ----------
// Gathers bf16 table; OUTPACK: write packed-split uint (next GEMM input), else f32.
template<int H, bool OUTPACK>
__global__ __launch_bounds__(256, 8) void gat_agg(const unsigned short* __restrict__ hp,
                                                  const float* __restrict__ s,
                                                  const float* __restrict__ d,
                                                  const int* __restrict__ offs,
                                                  const int* __restrict__ csr_src,
                                                  const float* __restrict__ bias,
                                                  void* __restrict__ outV, int N) {
    const int SW = (H == 4) ? 5 : 2;
    __shared__ float stash[4][64 * 5];
    int wv = threadIdx.x >> 6;
    int lane = threadIdx.x & 63;
    int node = (blockIdx.x * blockDim.x + threadIdx.x) >> 6;
    if (node >= N) return;
    float* st = stash[wv];
    int e0 = offs[node], e1 = offs[node + 1];

    float dd[H];
    #pragma unroll
    for (int h = 0; h < H; ++h) dd[h] = d[node * H + h];

    const int hd = (H == 4) ? (lane >> 4) : 0;

    float mrun = -INFINITY;
    float acc0 = 0.f, acc1 = 0.f, acc2 = 0.f, acc3 = 0.f, den = 0.f;

    for (int base = e0; base < e1; base += 64) {
        int cnt = min(64, e1 - base);
        float ev[H];
        #pragma unroll
        for (int h = 0; h < H; ++h) ev[h] = -INFINITY;
        if (lane < cnt) {
            int src = csr_src[base + lane];
            if (H == 4) {
                float4 sv = *(const float4*)&s[src * 4];
                ev[0] = lrelu(sv.x + dd[0]); ev[1] = lrelu(sv.y + dd[1]);
                ev[2] = lrelu(sv.z + dd[2]); ev[3] = lrelu(sv.w + dd[3]);
                st[lane * 5 + 0] = ev[0]; st[lane * 5 + 1] = ev[1];
                st[lane * 5 + 2] = ev[2]; st[lane * 5 + 3] = ev[3];
                st[lane * 5 + 4] = __int_as_float(src);
            } else {
                ev[0] = lrelu(s[src] + dd[0]);
                st[lane * 2 + 0] = ev[0];
                st[lane * 2 + 1] = __int_as_float(src);
            }
        }
        float mc[H];
        #pragma unroll
        for (int h = 0; h < H; ++h) {
            float m = ev[h];
            #pragma unroll
            for (int off = 32; off; off >>= 1) m = fmaxf(m, __shfl_xor(m, off));
            mc[h] = m;
        }
        float mch = mc[0];
        if (H == 4)
            mch = (lane & 32) ? ((lane & 16) ? mc[3] : mc[2]) : ((lane & 16) ? mc[1] : mc[0]);
        float mnew = fmaxf(mrun, mch);
        float scale = __expf(mrun - mnew);
        acc0 *= scale; acc1 *= scale; acc2 *= scale; acc3 *= scale; den *= scale;
        mrun = mnew;

        int k = 0;
        for (; k + 4 <= cnt; k += 4) {
            float ea = st[(k + 0) * SW + hd];
            float eb = st[(k + 1) * SW + hd];
            float ec = st[(k + 2) * SW + hd];
            float ed = st[(k + 3) * SW + hd];
            int sa = __float_as_int(st[(k + 0) * SW + SW - 1]);
            int sb = __float_as_int(st[(k + 1) * SW + SW - 1]);
            int sc = __float_as_int(st[(k + 2) * SW + SW - 1]);
            int sd_ = __float_as_int(st[(k + 3) * SW + SW - 1]);
            float pa = __expf(ea - mrun);
            float pb = __expf(eb - mrun);
            float pc = __expf(ec - mrun);
            float pd = __expf(ed - mrun);
            den += (pa + pb) + (pc + pd);
            if (H == 4) {
                uint2 ua = *(const uint2*)&hp[(size_t)sa * 256 + lane * 4];
                uint2 ub = *(const uint2*)&hp[(size_t)sb * 256 + lane * 4];
                uint2 uc = *(const uint2*)&hp[(size_t)sc * 256 + lane * 4];
                uint2 ud = *(const uint2*)&hp[(size_t)sd_ * 256 + lane * 4];
                acc0 = fmaf(pa, __uint_as_float((ua.x & 0xffffu) << 16), acc0);
                acc1 = fmaf(pa, __uint_as_float(ua.x & 0xffff0000u), acc1);
                acc2 = fmaf(pa, __uint_as_float((ua.y & 0xffffu) << 16), acc2);
                acc3 = fmaf(pa, __uint_as_float(ua.y & 0xffff0000u), acc3);
                acc0 = fmaf(pb, __uint_as_float((ub.x & 0xffffu) << 16), acc0);
                acc1 = fmaf(pb, __uint_as_float(ub.x & 0xffff0000u), acc1);
                acc2 = fmaf(pb, __uint_as_float((ub.y & 0xffffu) << 16), acc2);
                acc3 = fmaf(pb, __uint_as_float(ub.y & 0xffff0000u), acc3);
                acc0 = fmaf(pc, __uint_as_float((uc.x & 0xffffu) << 16), acc0);
                acc1 = fmaf(pc, __uint_as_float(uc.x & 0xffff0000u), acc1);
                acc2 = fmaf(pc, __uint_as_float((uc.y & 0xffffu) << 16), acc2);
                acc3 = fmaf(pc, __uint_as_float(uc.y & 0xffff0000u), acc3);
                acc0 = fmaf(pd, __uint_as_float((ud.x & 0xffffu) << 16), acc0);
                acc1 = fmaf(pd, __uint_as_float(ud.x & 0xffff0000u), acc1);
                acc2 = fmaf(pd, __uint_as_float((ud.y & 0xffffu) << 16), acc2);
                acc3 = fmaf(pd, __uint_as_float(ud.y & 0xffff0000u), acc3);
            } else {
                float ha = bf16_to_f32(hp[(size_t)sa * 64 + lane]);
                float hb = bf16_to_f32(hp[(size_t)sb * 64 + lane]);
                float hc = bf16_to_f32(hp[(size_t)sc * 64 + lane]);
                float hdv = bf16_to_f32(hp[(size_t)sd_ * 64 + lane]);
                acc0 = fmaf(pa, ha, acc0);
                acc0 = fmaf(pb, hb, acc0);
                acc0 = fmaf(pc, hc, acc0);
                acc0 = fmaf(pd, hdv, acc0);
            }
        }
        for (; k < cnt; ++k) {
            float e = st[k * SW + hd];
            int src = __float_as_int(st[k * SW + SW - 1]);
            float p = __expf(e - mrun);
            den += p;
            if (H == 4) {
                uint2 uv = *(const uint2*)&hp[(size_t)src * 256 + lane * 4];
                acc0 = fmaf(p, __uint_as_float((uv.x & 0xffffu) << 16), acc0);
                acc1 = fmaf(p, __uint_as_float(uv.x & 0xffff0000u), acc1);
                acc2 = fmaf(p, __uint_as_float((uv.y & 0xffffu) << 16), acc2);
                acc3 = fmaf(p, __uint_as_float(uv.y & 0xffff0000u), acc3);
            } else {
                acc0 = fmaf(p, bf16_to_f32(hp[(size_t)src * 64 + lane]), acc0);
            }
        }
    }

    float inv = 1.0f / (den + 1e-16f);
    if (H == 4) {
        float4 bv = *(const float4*)&bias[lane * 4];
        float o0 = elu_f(acc0 * inv + bv.x);
        float o1 = elu_f(acc1 * inv + bv.y);
        float o2 = elu_f(acc2 * inv + bv.z);
        float o3 = elu_f(acc3 * inv + bv.w);
        if (OUTPACK) {
            uint4 q;
            q.x = pack_split(o0); q.y = pack_split(o1);
            q.z = pack_split(o2); q.w = pack_split(o3);
            *(uint4*)&((unsigned*)outV)[(size_t)node * 256 + lane * 4] = q;
        } else {
            float4 o = make_float4(o0, o1, o2, o3);
            *(float4*)&((float*)outV)[(size_t)node * 256 + lane * 4] = o;
        }
    } else {
        float o = elu_f(acc0 * inv + bias[lane]);
        if (OUTPACK) ((unsigned*)outV)[(size_t)node * 64 + lane] = pack_split(o);
        else         ((float*)outV)[(size_t)node * 64 + lane] = o;
    }
}

// ---------- pooling ----------
__global__ void pool_init(float* gsum, unsigned* gmax, int* gcnt) {
    int t = blockIdx.x * blockDim.x + threadIdx.x;
    if (t < NG * 64) { gsum[t] = 0.f; gmax[t] = enc_f32(-INFINITY); }
    if (t < NG) gcnt[t] = 0;
}

__global__ void pool_reduce(const float* __restrict__ h3, const int* __restrict__ batch,
                            float* __restrict__ gsum, unsigned* __restrict__ gmax,
                            int* __restrict__ gcnt, int N, int per) {
    int w = (blockIdx.x * blockDim.x + threadIdx.x) >> 6;
    int lane = threadIdx.x & 63;
    int n0 = w * per;
    int n1 = min(N, n0 + per);
    float lsum = 0.f, lmax = -INFINITY;
    int cur = -1, cnt = 0;
    for (int n = n0; n < n1; ++n) {
        int g = batch[n];
        if (g != cur) {
            if (cur >= 0) {
                atomicAdd(&gsum[cur * 64 + lane], lsum);
                atomicMax(&gmax[cur * 64 + lane], enc_f32(lmax));
                if (lane == 0) atomicAdd(&gcnt[cur], cnt);
            }
            cur = g; lsum = 0.f; lmax = -INFINITY; cnt = 0;
        }
        float v = h3[(size_t)n * 64 + lane];
        lsum += v; lmax = fmaxf(lmax, v); cnt++;
    }
    if (cur >= 0) {
        atomicAdd(&gsum[cur * 64 + lane], lsum);
        atomicMax(&gmax[cur * 64 + lane], enc_f32(lmax));
        if (lane == 0) atomicAdd(&gcnt[cur], cnt);
    }
}

// ---------- classifier: one block per graph ----------
__global__ __launch_bounds__(128) void classifier(const float* __restrict__ gsum,
                                                  const unsigned* __restrict__ gmax,
                                                  const int* __restrict__ gcnt,
                                                  const float* __restrict__ Wc1,
                                                  const float* __restrict__ bc1,
                                                  const float* __restrict__ Wc2,
                                                  const float* __restrict__ bc2,
                                                  float* __restrict__ out) {
    __shared__ float gv[128];
    __shared__ float z1[64];
    int g = blockIdx.x, t = threadIdx.x;
    int cnt = gcnt[g];
    if (t < 64) {
        gv[t] = gsum[g * 64 + t] / fmaxf((float)cnt, 1.f);
    } else {
        float mx = dec_f32(gmax[g * 64 + (t - 64)]);
        gv[t] = (cnt > 0) ? mx : 0.f;
    }
    __syncthreads();
    if (t < 64) {
        float a = bc1[t];
        for (int k = 0; k < 128; ++k) a = fmaf(Wc1[t * 128 + k], gv[k], a);
        z1[t] = a > 0.f ? a : 0.f;
    }
    __syncthreads();
    if (t < 10) {
        float a = bc2[t];
        for (int k = 0; k < 64; ++k) a = fmaf(Wc2[t * 64 + k], z1[k], a);
        out[g * 10 + t] = a;
    }
}

// ---------- launch ----------
extern "C" void kernel_launch(void* const* d_in, const int* in_sizes, int n_in,
                              void* d_out, int out_size, void* d_ws, size_t ws_size,
                              hipStream_t stream) {
    const float* x      = (const float*)d_in[0];
    const int*   ei     = (const int*)d_in[1];
    const int*   batch  = (const int*)d_in[2];
    const float* W_emb  = (const float*)d_in[3];
    const float* b_emb  = (const float*)d_in[4];
    const float* W1     = (const float*)d_in[5];
    const float* as1    = (const float*)d_in[6];
    const float* ad1    = (const float*)d_in[7];
    const float* b1     = (const float*)d_in[8];
    const float* W2     = (const float*)d_in[9];
    const float* as2    = (const float*)d_in[10];
    const float* ad2    = (const float*)d_in[11];
    const float* b2     = (const float*)d_in[12];
    const float* W3     = (const float*)d_in[13];
    const float* as3    = (const float*)d_in[14];
    const float* ad3    = (const float*)d_in[15];
    const float* b3     = (const float*)d_in[16];
    const float* Wc1    = (const float*)d_in[17];
    const float* bc1    = (const float*)d_in[18];
    const float* Wc2    = (const float*)d_in[19];
    const float* bc2    = (const float*)d_in[20];

    const int N = in_sizes[0] / F_IN;   // 50000
    const int E = in_sizes[1] / 2;      // 800000
    const int ET = E + N;

    // workspace carve-up (256B aligned)
    size_t off = 0;
    auto alloc = [&](size_t bytes) -> void* {
        void* p = (char*)d_ws + off;
        off += (bytes + 255) & ~(size_t)255;
        return p;
    };
    unsigned* X1 = (unsigned*)alloc((size_t)N * 128 * 4);  // Xp packed; later H2b (bf16 [N][256])
    float*    X2 = (float*)alloc((size_t)N * 64 * 4);      // Aemb f32; later H3b (bf16 [N][64])
    unsigned* X3 = (unsigned*)alloc((size_t)N * 256 * 4);  // G packed; later C2p packed
    unsigned* X4 = (unsigned*)alloc((size_t)N * 256 * 4);  // C1p packed; later h3 f32
    float*    S  = (float*)alloc((size_t)N * 4 * 4);
    float*    D  = (float*)alloc((size_t)N * 4 * 4);
    unsigned short* WhE = (unsigned short*)alloc(64 * 128 * 2);
    unsigned short* WlE = (unsigned short*)alloc(64 * 128 * 2);
    unsigned short* Wh1 = (unsigned short*)alloc(256 * 64 * 2);
    unsigned short* Wl1 = (unsigned short*)alloc(256 * 64 * 2);
    unsigned short* Wh2 = (unsigned short*)alloc(256 * 256 * 2);
    unsigned short* Wl2 = (unsigned short*)alloc(256 * 256 * 2);
    unsigned short* Wh3 = (unsigned short*)alloc(64 * 256 * 2);
    unsigned short* Wl3 = (unsigned short*)alloc(64 * 256 * 2);
    float*    us1     = (float*)alloc(4 * 64 * 4);
    float*    ud1     = (float*)alloc(4 * 64 * 4);
    int*      offs    = (int*)alloc((size_t)(N + 1) * 4);
    int*      cnt     = (int*)alloc((size_t)N * 4);
    int*      bsum    = (int*)alloc(64 * 4);
    int*      csr_src = (int*)alloc((size_t)ET * 4);
    float*    gsum    = (float*)alloc(NG * 64 * 4);
    unsigned* gmax    = (unsigned*)alloc(NG * 64 * 4);
    int*      gcnt    = (int*)alloc(NG * 4);
    (void)ws_size; (void)n_in; (void)out_size;

    const int SCB = (N + 1023) / 1024;

    // pre-pack: x -> packed; weights -> dual hi/lo
    convert_pack<<<(N * 128 / 4 + 255) / 256, 256, 0, stream>>>(x, X1, N * 128);
    convert_dual<<<8, 256, 0, stream>>>(W_emb, WhE, WlE, 64 * 128);
    convert_dual<<<16, 256, 0, stream>>>(W1, Wh1, Wl1, 256 * 64);
    convert_dual<<<64, 256, 0, stream>>>(W2, Wh2, Wl2, 256 * 256);
    convert_dual<<<16, 256, 0, stream>>>(W3, Wh3, Wl3, 64 * 256);
    uvec_kernel<<<1, 256, 0, stream>>>(W1, as1, ad1, us1, ud1);

    // CSR build
    hipMemsetAsync(cnt, 0, (size_t)N * 4, stream);
    hist_kernel<<<(ET + 255) / 256, 256, 0, stream>>>(ei, cnt, E, N);
    scan1_kernel<<<SCB, 256, 0, stream>>>(cnt, offs, bsum, N);
    scan2_kernel<<<1, 64, 0, stream>>>(bsum, offs, SCB, N);
    scan3_kernel<<<SCB, 256, 0, stream>>>(offs, bsum, N);
    hipMemsetAsync(cnt, 0, (size_t)N * 4, stream);
    scatter_kernel<<<(ET + 255) / 256, 256, 0, stream>>>(ei, offs, cnt, csr_src, E, N);

    const int NWV = (N * 64 + 255) / 256;
    const int GB = (N + 63) / 64;

    // embedding: Aemb(f32) = x@W_embT + b_emb, fused s1,d1 via commute u-vectors
    gemm_nolds<128, 64, 4, true, false, false, 0><<<dim3(GB, 1), 256, 0, stream>>>(
        X1, 128, WhE, WlE, X2, 64, b_emb, us1, ud1, S, D, N);
    // layer-1 commuted aggregation (gathers f32 emb; outputs packed G)
    gat_agg_x<<<NWV, 256, 0, stream>>>(X2, S, D, offs, csr_src, X3, N);
    // per-head transform: C1p = packed(elu(G_h @ W1_hT + b1))
    gemm_nolds<64, 64, 0, false, true, true, 2><<<dim3(GB, 4), 256, 0, stream>>>(
        X3, 256, Wh1, Wl1, X4, 256, b1, nullptr, nullptr, nullptr, nullptr, N);
    // layer 2: H2b(bf16) = C1p@W2T, fused s2,d2
    gemm_nolds<256, 256, 4, false, false, false, 1><<<dim3(GB, 1), 256, 0, stream>>>(
        X4, 256, Wh2, Wl2, X1, 256, nullptr, as2, ad2, S, D, N);
    gat_agg<4, true><<<NWV, 256, 0, stream>>>((const unsigned short*)X1, S, D, offs, csr_src,
                                              b2, X3, N);
    // layer 3: H3b(bf16) = C2p@W3T, fused s3,d3
    gemm_nolds<256, 64, 1, true, false, false, 1><<<dim3(GB, 1), 256, 0, stream>>>(
        X3, 256, Wh3, Wl3, X2, 64, nullptr, as3, ad3, S, D, N);
    gat_agg<1, false><<<NWV, 256, 0, stream>>>((const unsigned short*)X2, S, D, offs, csr_src,
                                               b3, X4, N);

    // pooling + classifier (h3 f32 in X4)
    pool_init<<<16, 256, 0, stream>>>(gsum, gmax, gcnt);
    int per = (N + 255) / 256;
    pool_reduce<<<64, 256, 0, stream>>>((const float*)X4, batch, gsum, gmax, gcnt, N, per);
    classifier<<<NG, 128, 0, stream>>>(gsum, gmax, gcnt, Wc1, bc1, Wc2, bc2, (float*)d_out);
}

// Round 9
// 627.428 us; speedup vs baseline: 1.0305x; 1.0305x over previous
//
#include <hip/hip_runtime.h>
#include <math.h>

#define NG 64          // graphs
#define F_IN 128
#define NEG_SLOPE 0.2f

typedef __attribute__((ext_vector_type(8))) short s16x8;
typedef __attribute__((ext_vector_type(4))) float f32x4;

// ---------- helpers ----------
static __device__ __forceinline__ float elu_f(float x) { return x > 0.f ? x : expm1f(x); }
static __device__ __forceinline__ float lrelu(float x) { return x > 0.f ? x : NEG_SLOPE * x; }
static __device__ __forceinline__ unsigned enc_f32(float x) {
    unsigned u = __float_as_uint(x);
    return (u & 0x80000000u) ? ~u : (u | 0x80000000u);
}
static __device__ __forceinline__ float dec_f32(unsigned u) {
    unsigned b = (u & 0x80000000u) ? (u & 0x7fffffffu) : ~u;
    return __uint_as_float(b);
}
static __device__ __forceinline__ unsigned short bf16_rn(float x) {
    unsigned u = __float_as_uint(x);
    unsigned r = u + 0x7FFFu + ((u >> 16) & 1u);
    return (unsigned short)(r >> 16);
}
static __device__ __forceinline__ float bf16_to_f32(unsigned short h) {
    return __uint_as_float(((unsigned)h) << 16);
}

// MFMA fragment-order layout: element (row,k) of a [R][K] bf16 matrix.
// 16-row x 32-k tile = 512 elems, stored lane-major: lane (kg*16+lj) owns
// (row=lj, k=kg*8..+7) contiguous -> one wave fragment = 1KB contiguous.
static __device__ __forceinline__ size_t fragaddr(int row, int k, int K) {
    return ((size_t)(row >> 4) * (K >> 5) + (k >> 5)) * 512
         + (size_t)(((k & 31) >> 3) * 128 + (row & 15) * 8 + (k & 7));
}

// ---------- pre-pack: f32 [R][K] -> frag-order hi/lo bf16 ----------
__global__ void convert_frag(const float* __restrict__ in, unsigned short* __restrict__ hi,
                             unsigned short* __restrict__ lo, int R, int K) {
    int t = blockIdx.x * blockDim.x + threadIdx.x;
    if (t * 8 >= R * K) return;
    int row = (t * 8) / K;
    int k0 = (t * 8) % K;
    float4 v0 = *(const float4*)&in[(size_t)row * K + k0];
    float4 v1 = *(const float4*)&in[(size_t)row * K + k0 + 4];
    float v[8] = {v0.x, v0.y, v0.z, v0.w, v1.x, v1.y, v1.z, v1.w};
    unsigned short h[8], l[8];
    #pragma unroll
    for (int i = 0; i < 8; ++i) {
        h[i] = bf16_rn(v[i]);
        l[i] = bf16_rn(v[i] - bf16_to_f32(h[i]));
    }
    size_t a = fragaddr(row, k0, K);
    *(ushort4*)&hi[a]     = make_ushort4(h[0], h[1], h[2], h[3]);
    *(ushort4*)&hi[a + 4] = make_ushort4(h[4], h[5], h[6], h[7]);
    *(ushort4*)&lo[a]     = make_ushort4(l[0], l[1], l[2], l[3]);
    *(ushort4*)&lo[a + 4] = make_ushort4(l[4], l[5], l[6], l[7]);
}

// u[h][i] = sum_o W1[h*64+o][i] * a[h][o]   (layer-1 commute attention scalars)
__global__ void uvec_kernel(const float* __restrict__ W1, const float* __restrict__ a1s,
                            const float* __restrict__ a1d,
                            float* __restrict__ us, float* __restrict__ ud) {
    int h = threadIdx.x >> 6;
    int i = threadIdx.x & 63;
    float s = 0.f, d = 0.f;
    for (int o = 0; o < 64; ++o) {
        float w = W1[(h * 64 + o) * 64 + i];
        s = fmaf(w, a1s[h * 64 + o], s);
        d = fmaf(w, a1d[h * 64 + o], d);
    }
    us[h * 64 + i] = s;
    ud[h * 64 + i] = d;
}

// ---------- CSR build ----------
__global__ void hist_kernel(const int* __restrict__ ei, int* __restrict__ cnt, int E, int N) {
    int e = blockIdx.x * blockDim.x + threadIdx.x;
    int ET = E + N;
    if (e >= ET) return;
    int dst = (e < E) ? ei[E + e] : (e - E);
    atomicAdd(&cnt[dst], 1);
}

__global__ void scan1_kernel(const int* __restrict__ cnt, int* __restrict__ excl,
                             int* __restrict__ bsum, int n) {
    __shared__ int sm[256];
    int t = threadIdx.x;
    int base = blockIdx.x * 1024 + t * 4;
    int v[4];
    #pragma unroll
    for (int u = 0; u < 4; ++u) { int idx = base + u; v[u] = (idx < n) ? cnt[idx] : 0; }
    int tsum = v[0] + v[1] + v[2] + v[3];
    sm[t] = tsum;
    __syncthreads();
    for (int off = 1; off < 256; off <<= 1) {
        int y = (t >= off) ? sm[t - off] : 0;
        __syncthreads();
        sm[t] += y;
        __syncthreads();
    }
    int run = sm[t] - tsum;
    #pragma unroll
    for (int u = 0; u < 4; ++u) {
        int idx = base + u;
        if (idx < n) excl[idx] = run;
        run += v[u];
    }
    if (t == 255) bsum[blockIdx.x] = sm[255];
}

__global__ void scan2_kernel(int* __restrict__ bsum, int* __restrict__ offs, int nb, int n) {
    if (blockIdx.x == 0 && threadIdx.x == 0) {
        int run = 0;
        for (int b = 0; b < nb; ++b) { int t = bsum[b]; bsum[b] = run; run += t; }
        offs[n] = run;
    }
}

__global__ void scan3_kernel(int* __restrict__ offs, const int* __restrict__ bsum, int n) {
    int base = blockIdx.x * 1024 + threadIdx.x * 4;
    int add = bsum[blockIdx.x];
    #pragma unroll
    for (int u = 0; u < 4; ++u) { int idx = base + u; if (idx < n) offs[idx] += add; }
}

__global__ void scatter_kernel(const int* __restrict__ ei, const int* __restrict__ offs,
                               int* __restrict__ cursor, int* __restrict__ csr_src, int E, int N) {
    int e = blockIdx.x * blockDim.x + threadIdx.x;
    int ET = E + N;
    if (e >= ET) return;
    int src, dst;
    if (e < E) { src = ei[e]; dst = ei[E + e]; }
    else       { src = e - E; dst = e - E; }
    int pos = offs[dst] + atomicAdd(&cursor[dst], 1);
    csr_src[pos] = src;
}

// ---------- frag-order LDS-free split-bf16 MFMA GEMM ----------
// A, W in frag-order hi/lo ushort arrays. All loads are 16B/lane coalesced.
// BN==256: block = 64 rows x 256 cols; 4 waves split cols (cbase=w*64), RF=4 over rows.
// BN==64:  block = 256 rows x 64 cols; 4 waves split rows (rbase=w*64), RF=4.
// OUTM: 0=f32 row-major, 1=bf16 row-major, 3=frag-order split (Ohi/Olo).
template<int K, int AK, int BN, int HATT, bool SHARED, bool SLICED, bool DO_ELU, int OUTM>
__global__ __launch_bounds__(256) void gemm_frag(const unsigned short* __restrict__ Ahi,
                                                 const unsigned short* __restrict__ Alo,
                                                 const unsigned short* __restrict__ Whi,
                                                 const unsigned short* __restrict__ Wlo,
                                                 void* __restrict__ OutV,
                                                 unsigned short* __restrict__ Ohi,
                                                 unsigned short* __restrict__ Olo,
                                                 int M,
                                                 const float* __restrict__ bias,
                                                 const float* __restrict__ asrc,
                                                 const float* __restrict__ adst,
                                                 float* __restrict__ S, float* __restrict__ D,
                                                 int N) {
    const int t = threadIdx.x;
    const int lane = t & 63;
    const int w = t >> 6;
    const int lj = lane & 15;
    const int kg = lane >> 4;
    const int n0 = blockIdx.x * ((BN == 256) ? 64 : 256);
    const int m0 = blockIdx.y * BN;
    const int rbase = (BN == 256) ? 0 : w * 64;
    const int cbase = (BN == 256) ? w * 64 : 0;
    const int aoff = SLICED ? blockIdx.y * K : 0;
    const unsigned short* __restrict__ WhiB = SLICED ? Whi + (size_t)blockIdx.y * BN * K : Whi;
    const unsigned short* __restrict__ WloB = SLICED ? Wlo + (size_t)blockIdx.y * BN * K : Wlo;

    f32x4 acc[4][4];
    #pragma unroll
    for (int rf = 0; rf < 4; ++rf)
        #pragma unroll
        for (int cf = 0; cf < 4; ++cf) acc[rf][cf] = (f32x4){0.f, 0.f, 0.f, 0.f};

    for (int kc = 0; kc < K; kc += 32) {
        s16x8 ah[4], al[4];
        #pragma unroll
        for (int rf = 0; rf < 4; ++rf) {
            size_t a = fragaddr(n0 + rbase + rf * 16 + lj, aoff + kc + kg * 8, AK);
            ah[rf] = *(const s16x8*)&Ahi[a];
            al[rf] = *(const s16x8*)&Alo[a];
        }
        #pragma unroll
        for (int cf = 0; cf < 4; ++cf) {
            int bcol = (SLICED ? 0 : m0) + cbase + cf * 16 + lj;
            size_t b = fragaddr(bcol, kc + kg * 8, K);
            s16x8 bh = *(const s16x8*)&WhiB[b];
            s16x8 bl = *(const s16x8*)&WloB[b];
            #pragma unroll
            for (int rf = 0; rf < 4; ++rf) {
                acc[rf][cf] = __builtin_amdgcn_mfma_f32_16x16x32_bf16(ah[rf], bh, acc[rf][cf], 0, 0, 0);
                acc[rf][cf] = __builtin_amdgcn_mfma_f32_16x16x32_bf16(ah[rf], bl, acc[rf][cf], 0, 0, 0);
                acc[rf][cf] = __builtin_amdgcn_mfma_f32_16x16x32_bf16(al[rf], bh, acc[rf][cf], 0, 0, 0);
            }
        }
    }

    // epilogue: C/D layout col=lane&15, row=(lane>>4)*4+reg
    #pragma unroll
    for (int cf = 0; cf < 4; ++cf) {
        int gcol = m0 + cbase + cf * 16 + lj;
        float bv = bias ? bias[gcol] : 0.f;
        #pragma unroll
        for (int rf = 0; rf < 4; ++rf) {
            #pragma unroll
            for (int r = 0; r < 4; ++r) {
                int gn = n0 + rbase + rf * 16 + (lane >> 4) * 4 + r;
                if (gn < N) {
                    float o = acc[rf][cf][r] + bv;
                    if (DO_ELU) o = elu_f(o);
                    if (OUTM == 0) {
                        ((float*)OutV)[(size_t)gn * M + gcol] = o;
                    } else if (OUTM == 1) {
                        ((unsigned short*)OutV)[(size_t)gn * M + gcol] = bf16_rn(o);
                    } else {
                        unsigned short hv = bf16_rn(o);
                        unsigned short lv = bf16_rn(o - bf16_to_f32(hv));
                        size_t a2 = fragaddr(gn, gcol, M);
                        Ohi[a2] = hv; Olo[a2] = lv;
                    }
                }
            }
        }
    }
    // fused attention scalars (f32 acc, post-bias)
    if (HATT > 0) {
        const int HS = SHARED ? HATT : 1;
        #pragma unroll
        for (int hh = 0; hh < HS; ++hh) {
            const int head = SHARED ? hh : w;
            float aw[4], dw[4], bw[4];
            #pragma unroll
            for (int c2 = 0; c2 < 4; ++c2) {
                aw[c2] = asrc[head * 64 + c2 * 16 + lj];
                dw[c2] = adst[head * 64 + c2 * 16 + lj];
                bw[c2] = bias ? bias[m0 + cbase + c2 * 16 + lj] : 0.f;
            }
            #pragma unroll
            for (int rf = 0; rf < 4; ++rf) {
                #pragma unroll
                for (int r = 0; r < 4; ++r) {
                    float sp = 0.f, dp = 0.f;
                    #pragma unroll
                    for (int c2 = 0; c2 < 4; ++c2) {
                        float vv = acc[rf][c2][r] + bw[c2];
                        sp = fmaf(vv, aw[c2], sp);
                        dp = fmaf(vv, dw[c2], dp);
                    }
                    #pragma unroll
                    for (int off = 1; off < 16; off <<= 1) {
                        sp += __shfl_xor(sp, off);
                        dp += __shfl_xor(dp, off);
                    }
                    if (lj == 0) {
                        int gn = n0 + rbase + rf * 16 + (lane >> 4) * 4 + r;
                        if (gn < N) { S[gn * HATT + head] = sp; D[gn * HATT + head] = dp; }
                    }
                }
            }
        }
    }
}

// ---------- layer-1 aggregation over raw emb (commuted); outputs frag-order split ----------
__global__ __launch_bounds__(256, 8) void gat_agg_x(const float* __restrict__ xA,  // [N][64] f32
                                                    const float* __restrict__ s,   // [N][4]
                                                    const float* __restrict__ d,
                                                    const int* __restrict__ offs,
                                                    const int* __restrict__ csr_src,
                                                    unsigned short* __restrict__ Gh,
                                                    unsigned short* __restrict__ Gl,
                                                    int N) {
    __shared__ float stash[4][64 * 5];
    int wv = threadIdx.x >> 6;
    int lane = threadIdx.x & 63;
    int node = (blockIdx.x * blockDim.x + threadIdx.x) >> 6;
    if (node >= N) return;
    float* st = stash[wv];
    int e0 = offs[node], e1 = offs[node + 1];
    float4 dv4 = *(const float4*)&d[node * 4];
    float dd[4] = {dv4.x, dv4.y, dv4.z, dv4.w};
    float mrun[4] = {-INFINITY, -INFINITY, -INFINITY, -INFINITY};
    float den[4] = {0.f, 0.f, 0.f, 0.f};
    float acc[4] = {0.f, 0.f, 0.f, 0.f};

    for (int base = e0; base < e1; base += 64) {
        int cnt = min(64, e1 - base);
        float ev[4] = {-INFINITY, -INFINITY, -INFINITY, -INFINITY};
        if (lane < cnt) {
            int src = csr_src[base + lane];
            float4 sv = *(const float4*)&s[src * 4];
            ev[0] = lrelu(sv.x + dd[0]); ev[1] = lrelu(sv.y + dd[1]);
            ev[2] = lrelu(sv.z + dd[2]); ev[3] = lrelu(sv.w + dd[3]);
            st[lane * 5 + 0] = ev[0]; st[lane * 5 + 1] = ev[1];
            st[lane * 5 + 2] = ev[2]; st[lane * 5 + 3] = ev[3];
            st[lane * 5 + 4] = __int_as_float(src);
        }
        #pragma unroll
        for (int h = 0; h < 4; ++h) {
            float m = ev[h];
            #pragma unroll
            for (int off = 32; off; off >>= 1) m = fmaxf(m, __shfl_xor(m, off));
            float mnew = fmaxf(mrun[h], m);
            float scale = __expf(mrun[h] - mnew);
            acc[h] *= scale; den[h] *= scale;
            mrun[h] = mnew;
        }
        int k = 0;
        for (; k + 4 <= cnt; k += 4) {
            int si[4];
            #pragma unroll
            for (int u = 0; u < 4; ++u) si[u] = __float_as_int(st[(k + u) * 5 + 4]);
            float vx[4];
            #pragma unroll
            for (int u = 0; u < 4; ++u) vx[u] = xA[(size_t)si[u] * 64 + lane];
            #pragma unroll
            for (int u = 0; u < 4; ++u) {
                #pragma unroll
                for (int h = 0; h < 4; ++h) {
                    float p = __expf(st[(k + u) * 5 + h] - mrun[h]);
                    den[h] += p;
                    acc[h] = fmaf(p, vx[u], acc[h]);
                }
            }
        }
        for (; k < cnt; ++k) {
            int src = __float_as_int(st[k * 5 + 4]);
            float v = xA[(size_t)src * 64 + lane];
            #pragma unroll
            for (int h = 0; h < 4; ++h) {
                float p = __expf(st[k * 5 + h] - mrun[h]);
                den[h] += p;
                acc[h] = fmaf(p, v, acc[h]);
            }
        }
    }
    #pragma unroll
    for (int h = 0; h < 4; ++h) {
        float v = acc[h] / (den[h] + 1e-16f);
        unsigned short hv = bf16_rn(v);
        unsigned short lv = bf16_rn(v - bf16_to_f32(hv));
        size_t a = fragaddr(node, h * 64 + lane, 256);
        Gh[a] = hv; Gl[a] = lv;
    }
}

// ---------- GAT aggregation: one wave per dst node, chunked online softmax ----------
// Gathers bf16 row-major table. H=4+FRAGOUT: write frag-order split; H=1: f32 row-major.
template<int H, bool FRAGOUT>
__global__ __launch_bounds__(256, 8) void gat_agg(const unsigned short* __restrict__ hp,
                                                  const float* __restrict__ s,
                                                  const float* __restrict__ d,
                                                  const int* __restrict__ offs,
                                                  const int* __restrict__ csr_src,
                                                  const float* __restrict__ bias,
                                                  float* __restrict__ outF,
                                                  unsigned short* __restrict__ outHi,
                                                  unsigned short* __restrict__ outLo,
                                                  int N) {
    const int SW = (H == 4) ? 5 : 2;
    __shared__ float stash[4][64 * 5];
    int wv = threadIdx.x >> 6;
    int lane = threadIdx.x & 63;
    int node = (blockIdx.x * blockDim.x + threadIdx.x) >> 6;
    if (node >= N) return;
    float* st = stash[wv];
    int e0 = offs[node], e1 = offs[node + 1];

    float dd[H];
    #pragma unroll
    for (int h = 0; h < H; ++h) dd[h] = d[node * H + h];

    const int hd = (H == 4) ? (lane >> 4) : 0;

    float mrun = -INFINITY;
    float acc0 = 0.f, acc1 = 0.f, acc2 = 0.f, acc3 = 0.f, den = 0.f;

    for (int base = e0; base < e1; base += 64) {
        int cnt = min(64, e1 - base);
        float ev[H];
        #pragma unroll
        for (int h = 0; h < H; ++h) ev[h] = -INFINITY;
        if (lane < cnt) {
            int src = csr_src[base + lane];
            if (H == 4) {
                float4 sv = *(const float4*)&s[src * 4];
                ev[0] = lrelu(sv.x + dd[0]); ev[1] = lrelu(sv.y + dd[1]);
                ev[2] = lrelu(sv.z + dd[2]); ev[3] = lrelu(sv.w + dd[3]);
                st[lane * 5 + 0] = ev[0]; st[lane * 5 + 1] = ev[1];
                st[lane * 5 + 2] = ev[2]; st[lane * 5 + 3] = ev[3];
                st[lane * 5 + 4] = __int_as_float(src);
            } else {
                ev[0] = lrelu(s[src] + dd[0]);
                st[lane * 2 + 0] = ev[0];
                st[lane * 2 + 1] = __int_as_float(src);
            }
        }
        float mc[H];
        #pragma unroll
        for (int h = 0; h < H; ++h) {
            float m = ev[h];
            #pragma unroll
            for (int off = 32; off; off >>= 1) m = fmaxf(m, __shfl_xor(m, off));
            mc[h] = m;
        }
        float mch = mc[0];
        if (H == 4)
            mch = (lane & 32) ? ((lane & 16) ? mc[3] : mc[2]) : ((lane & 16) ? mc[1] : mc[0]);
        float mnew = fmaxf(mrun, mch);
        float scale = __expf(mrun - mnew);
        acc0 *= scale; acc1 *= scale; acc2 *= scale; acc3 *= scale; den *= scale;
        mrun = mnew;

        int k = 0;
        for (; k + 4 <= cnt; k += 4) {
            float ea = st[(k + 0) * SW + hd];
            float eb = st[(k + 1) * SW + hd];
            float ec = st[(k + 2) * SW + hd];
            float ed = st[(k + 3) * SW + hd];
            int sa = __float_as_int(st[(k + 0) * SW + SW - 1]);
            int sb = __float_as_int(st[(k + 1) * SW + SW - 1]);
            int sc = __float_as_int(st[(k + 2) * SW + SW - 1]);
            int sd_ = __float_as_int(st[(k + 3) * SW + SW - 1]);
            float pa = __expf(ea - mrun);
            float pb = __expf(eb - mrun);
            float pc = __expf(ec - mrun);
            float pd = __expf(ed - mrun);
            den += (pa + pb) + (pc + pd);
            if (H == 4) {
                uint2 ua = *(const uint2*)&hp[(size_t)sa * 256 + lane * 4];
                uint2 ub = *(const uint2*)&hp[(size_t)sb * 256 + lane * 4];
                uint2 uc = *(const uint2*)&hp[(size_t)sc * 256 + lane * 4];
                uint2 ud = *(const uint2*)&hp[(size_t)sd_ * 256 + lane * 4];
                acc0 = fmaf(pa, __uint_as_float((ua.x & 0xffffu) << 16), acc0);
                acc1 = fmaf(pa, __uint_as_float(ua.x & 0xffff0000u), acc1);
                acc2 = fmaf(pa, __uint_as_float((ua.y & 0xffffu) << 16), acc2);
                acc3 = fmaf(pa, __uint_as_float(ua.y & 0xffff0000u), acc3);
                acc0 = fmaf(pb, __uint_as_float((ub.x & 0xffffu) << 16), acc0);
                acc1 = fmaf(pb, __uint_as_float(ub.x & 0xffff0000u), acc1);
                acc2 = fmaf(pb, __uint_as_float((ub.y & 0xffffu) << 16), acc2);
                acc3 = fmaf(pb, __uint_as_float(ub.y & 0xffff0000u), acc3);
                acc0 = fmaf(pc, __uint_as_float((uc.x & 0xffffu) << 16), acc0);
                acc1 = fmaf(pc, __uint_as_float(uc.x & 0xffff0000u), acc1);
                acc2 = fmaf(pc, __uint_as_float((uc.y & 0xffffu) << 16), acc2);
                acc3 = fmaf(pc, __uint_as_float(uc.y & 0xffff0000u), acc3);
                acc0 = fmaf(pd, __uint_as_float((ud.x & 0xffffu) << 16), acc0);
                acc1 = fmaf(pd, __uint_as_float(ud.x & 0xffff0000u), acc1);
                acc2 = fmaf(pd, __uint_as_float((ud.y & 0xffffu) << 16), acc2);
                acc3 = fmaf(pd, __uint_as_float(ud.y & 0xffff0000u), acc3);
            } else {
                float ha = bf16_to_f32(hp[(size_t)sa * 64 + lane]);
                float hb = bf16_to_f32(hp[(size_t)sb * 64 + lane]);
                float hc = bf16_to_f32(hp[(size_t)sc * 64 + lane]);
                float hdv = bf16_to_f32(hp[(size_t)sd_ * 64 + lane]);
                acc0 = fmaf(pa, ha, acc0);
                acc0 = fmaf(pb, hb, acc0);
                acc0 = fmaf(pc, hc, acc0);
                acc0 = fmaf(pd, hdv, acc0);
            }
        }
        for (; k < cnt; ++k) {
            float e = st[k * SW + hd];
            int src = __float_as_int(st[k * SW + SW - 1]);
            float p = __expf(e - mrun);
            den += p;
            if (H == 4) {
                uint2 uv = *(const uint2*)&hp[(size_t)src * 256 + lane * 4];
                acc0 = fmaf(p, __uint_as_float((uv.x & 0xffffu) << 16), acc0);
                acc1 = fmaf(p, __uint_as_float(uv.x & 0xffff0000u), acc1);
                acc2 = fmaf(p, __uint_as_float((uv.y & 0xffffu) << 16), acc2);
                acc3 = fmaf(p, __uint_as_float(uv.y & 0xffff0000u), acc3);
            } else {
                acc0 = fmaf(p, bf16_to_f32(hp[(size_t)src * 64 + lane]), acc0);
            }
        }
    }

    float inv = 1.0f / (den + 1e-16f);
    if (H == 4) {
        float4 bv = *(const float4*)&bias[lane * 4];
        float o0 = elu_f(acc0 * inv + bv.x);
        float o1 = elu_f(acc1 * inv + bv.y);
        float o2 = elu_f(acc2 * inv + bv.z);
        float o3 = elu_f(acc3 * inv + bv.w);
        if (FRAGOUT) {
            unsigned short h0 = bf16_rn(o0), h1 = bf16_rn(o1), h2 = bf16_rn(o2), h3 = bf16_rn(o3);
            ushort4 hq = make_ushort4(h0, h1, h2, h3);
            ushort4 lq = make_ushort4(bf16_rn(o0 - bf16_to_f32(h0)),
                                      bf16_rn(o1 - bf16_to_f32(h1)),
                                      bf16_rn(o2 - bf16_to_f32(h2)),
                                      bf16_rn(o3 - bf16_to_f32(h3)));
            size_t a = fragaddr(node, lane * 4, 256);
            *(ushort4*)&outHi[a] = hq;
            *(ushort4*)&outLo[a] = lq;
        } else {
            float4 o = make_float4(o0, o1, o2, o3);
            *(float4*)&outF[(size_t)node * 256 + lane * 4] = o;
        }
    } else {
        outF[(size_t)node * 64 + lane] = elu_f(acc0 * inv + bias[lane]);
    }
}

// ---------- pooling ----------
__global__ void pool_init(float* gsum, unsigned* gmax, int* gcnt) {
    int t = blockIdx.x * blockDim.x + threadIdx.x;
    if (t < NG * 64) { gsum[t] = 0.f; gmax[t] = enc_f32(-INFINITY); }
    if (t < NG) gcnt[t] = 0;
}

__global__ void pool_reduce(const float* __restrict__ h3, const int* __restrict__ batch,
                            float* __restrict__ gsum, unsigned* __restrict__ gmax,
                            int* __restrict__ gcnt, int N, int per) {
    int w = (blockIdx.x * blockDim.x + threadIdx.x) >> 6;
    int lane = threadIdx.x & 63;
    int n0 = w * per;
    int n1 = min(N, n0 + per);
    float lsum = 0.f, lmax = -INFINITY;
    int cur = -1, cnt = 0;
    for (int n = n0; n < n1; ++n) {
        int g = batch[n];
        if (g != cur) {
            if (cur >= 0) {
                atomicAdd(&gsum[cur * 64 + lane], lsum);
                atomicMax(&gmax[cur * 64 + lane], enc_f32(lmax));
                if (lane == 0) atomicAdd(&gcnt[cur], cnt);
            }
            cur = g; lsum = 0.f; lmax = -INFINITY; cnt = 0;
        }
        float v = h3[(size_t)n * 64 + lane];
        lsum += v; lmax = fmaxf(lmax, v); cnt++;
    }
    if (cur >= 0) {
        atomicAdd(&gsum[cur * 64 + lane], lsum);
        atomicMax(&gmax[cur * 64 + lane], enc_f32(lmax));
        if (lane == 0) atomicAdd(&gcnt[cur], cnt);
    }
}

// ---------- classifier: one block per graph ----------
__global__ __launch_bounds__(128) void classifier(const float* __restrict__ gsum,
                                                  const unsigned* __restrict__ gmax,
                                                  const int* __restrict__ gcnt,
                                                  const float* __restrict__ Wc1,
                                                  const float* __restrict__ bc1,
                                                  const float* __restrict__ Wc2,
                                                  const float* __restrict__ bc2,
                                                  float* __restrict__ out) {
    __shared__ float gv[128];
    __shared__ float z1[64];
    int g = blockIdx.x, t = threadIdx.x;
    int cnt = gcnt[g];
    if (t < 64) {
        gv[t] = gsum[g * 64 + t] / fmaxf((float)cnt, 1.f);
    } else {
        float mx = dec_f32(gmax[g * 64 + (t - 64)]);
        gv[t] = (cnt > 0) ? mx : 0.f;
    }
    __syncthreads();
    if (t < 64) {
        float a = bc1[t];
        for (int k = 0; k < 128; ++k) a = fmaf(Wc1[t * 128 + k], gv[k], a);
        z1[t] = a > 0.f ? a : 0.f;
    }
    __syncthreads();
    if (t < 10) {
        float a = bc2[t];
        for (int k = 0; k < 64; ++k) a = fmaf(Wc2[t * 64 + k], z1[k], a);
        out[g * 10 + t] = a;
    }
}

// ---------- launch ----------
extern "C" void kernel_launch(void* const* d_in, const int* in_sizes, int n_in,
                              void* d_out, int out_size, void* d_ws, size_t ws_size,
                              hipStream_t stream) {
    const float* x      = (const float*)d_in[0];
    const int*   ei     = (const int*)d_in[1];
    const int*   batch  = (const int*)d_in[2];
    const float* W_emb  = (const float*)d_in[3];
    const float* b_emb  = (const float*)d_in[4];
    const float* W1     = (const float*)d_in[5];
    const float* as1    = (const float*)d_in[6];
    const float* ad1    = (const float*)d_in[7];
    const float* b1     = (const float*)d_in[8];
    const float* W2     = (const float*)d_in[9];
    const float* as2    = (const float*)d_in[10];
    const float* ad2    = (const float*)d_in[11];
    const float* b2     = (const float*)d_in[12];
    const float* W3     = (const float*)d_in[13];
    const float* as3    = (const float*)d_in[14];
    const float* ad3    = (const float*)d_in[15];
    const float* b3     = (const float*)d_in[16];
    const float* Wc1    = (const float*)d_in[17];
    const float* bc1    = (const float*)d_in[18];
    const float* Wc2    = (const float*)d_in[19];
    const float* bc2    = (const float*)d_in[20];

    const int N = in_sizes[0] / F_IN;   // 50000
    const int E = in_sizes[1] / 2;      // 800000
    const int ET = E + N;
    const int GB64 = (N + 63) / 64;     // 782  (BN=256 gemm)
    const int GB256 = (N + 255) / 256;  // 196  (BN=64 gemms)
    const int ROWS_FR = GB256 * 256;    // 50176 (covers both tilings)
    const size_t FR128 = (size_t)(ROWS_FR / 16) * (128 / 32) * 512;  // x frag elems
    const size_t FR256 = (size_t)(ROWS_FR / 16) * (256 / 32) * 512;  // 256-wide frag elems

    // workspace carve-up (256B aligned)
    size_t off = 0;
    auto alloc = [&](size_t bytes) -> void* {
        void* p = (char*)d_ws + off;
        off += (bytes + 255) & ~(size_t)255;
        return p;
    };
    unsigned short* Xh  = (unsigned short*)alloc(FR128 * 2);
    unsigned short* Xl  = (unsigned short*)alloc(FR128 * 2);
    float*          Aemb= (float*)alloc((size_t)N * 64 * 4);    // emb f32; later H3b (bf16)
    unsigned short* Gh  = (unsigned short*)alloc(FR256 * 2);    // G frag; later C2 frag
    unsigned short* Gl  = (unsigned short*)alloc(FR256 * 2);
    unsigned short* C1h = (unsigned short*)alloc(FR256 * 2);
    unsigned short* C1l = (unsigned short*)alloc(FR256 * 2);
    unsigned short* H2b = (unsigned short*)alloc((size_t)N * 256 * 2);  // h2 bf16; later h3 f32
    unsigned short* WhE = (unsigned short*)alloc(64 * 128 * 2);
    unsigned short* WlE = (unsigned short*)alloc(64 * 128 * 2);
    unsigned short* Wh1 = (unsigned short*)alloc(256 * 64 * 2);
    unsigned short* Wl1 = (unsigned short*)alloc(256 * 64 * 2);
    unsigned short* Wh2 = (unsigned short*)alloc(256 * 256 * 2);
    unsigned short* Wl2 = (unsigned short*)alloc(256 * 256 * 2);
    unsigned short* Wh3 = (unsigned short*)alloc(64 * 256 * 2);
    unsigned short* Wl3 = (unsigned short*)alloc(64 * 256 * 2);
    float*    us1     = (float*)alloc(4 * 64 * 4);
    float*    ud1     = (float*)alloc(4 * 64 * 4);
    float*    S       = (float*)alloc((size_t)N * 4 * 4);
    float*    D       = (float*)alloc((size_t)N * 4 * 4);
    int*      offs    = (int*)alloc((size_t)(N + 1) * 4);
    int*      cnt     = (int*)alloc((size_t)N * 4);
    int*      bsum    = (int*)alloc(64 * 4);
    int*      csr_src = (int*)alloc((size_t)ET * 4);
    float*    gsum    = (float*)alloc(NG * 64 * 4);
    unsigned* gmax    = (unsigned*)alloc(NG * 64 * 4);
    int*      gcnt    = (int*)alloc(NG * 4);
    (void)ws_size; (void)n_in; (void)out_size;

    const int SCB = (N + 1023) / 1024;

    // pre-pack to fragment order
    convert_frag<<<(N * 128 / 8 + 255) / 256, 256, 0, stream>>>(x, Xh, Xl, N, 128);
    convert_frag<<<4, 256, 0, stream>>>(W_emb, WhE, WlE, 64, 128);
    convert_frag<<<8, 256, 0, stream>>>(W1, Wh1, Wl1, 256, 64);
    convert_frag<<<32, 256, 0, stream>>>(W2, Wh2, Wl2, 256, 256);
    convert_frag<<<8, 256, 0, stream>>>(W3, Wh3, Wl3, 64, 256);
    uvec_kernel<<<1, 256, 0, stream>>>(W1, as1, ad1, us1, ud1);

    // CSR build
    hipMemsetAsync(cnt, 0, (size_t)N * 4, stream);
    hist_kernel<<<(ET + 255) / 256, 256, 0, stream>>>(ei, cnt, E, N);
    scan1_kernel<<<SCB, 256, 0, stream>>>(cnt, offs, bsum, N);
    scan2_kernel<<<1, 64, 0, stream>>>(bsum, offs, SCB, N);
    scan3_kernel<<<SCB, 256, 0, stream>>>(offs, bsum, N);
    hipMemsetAsync(cnt, 0, (size_t)N * 4, stream);
    scatter_kernel<<<(ET + 255) / 256, 256, 0, stream>>>(ei, offs, cnt, csr_src, E, N);

    const int NWV = (N * 64 + 255) / 256;

    // embedding: Aemb(f32) = x@W_embT + b_emb, fused s1,d1 via commute u-vectors
    gemm_frag<128, 128, 64, 4, true, false, false, 0><<<dim3(GB256, 1), 256, 0, stream>>>(
        Xh, Xl, WhE, WlE, Aemb, nullptr, nullptr, 64, b_emb, us1, ud1, S, D, N);
    // layer-1 commuted aggregation (gathers f32 emb; outputs frag G)
    gat_agg_x<<<NWV, 256, 0, stream>>>(Aemb, S, D, offs, csr_src, Gh, Gl, N);
    // per-head transform: C1 = frag(elu(G_h @ W1_hT + b1))
    gemm_frag<64, 256, 64, 0, false, true, true, 3><<<dim3(GB256, 4), 256, 0, stream>>>(
        Gh, Gl, Wh1, Wl1, nullptr, C1h, C1l, 256, b1, nullptr, nullptr, nullptr, nullptr, N);
    // layer 2: H2b(bf16) = C1@W2T, fused s2,d2
    gemm_frag<256, 256, 256, 4, false, false, false, 1><<<dim3(GB64, 1), 256, 0, stream>>>(
        C1h, C1l, Wh2, Wl2, H2b, nullptr, nullptr, 256, nullptr, as2, ad2, S, D, N);
    gat_agg<4, true><<<NWV, 256, 0, stream>>>(H2b, S, D, offs, csr_src, b2,
                                              nullptr, Gh, Gl, N);
    // layer 3: H3b(bf16, in Aemb buffer) = C2@W3T, fused s3,d3
    gemm_frag<256, 256, 64, 1, true, false, false, 1><<<dim3(GB256, 1), 256, 0, stream>>>(
        Gh, Gl, Wh3, Wl3, (unsigned short*)Aemb, nullptr, nullptr, 64, nullptr, as3, ad3, S, D, N);
    gat_agg<1, false><<<NWV, 256, 0, stream>>>((const unsigned short*)Aemb, S, D, offs, csr_src,
                                               b3, (float*)H2b, nullptr, nullptr, N);

    // pooling + classifier (h3 f32 in H2b buffer)
    pool_init<<<16, 256, 0, stream>>>(gsum, gmax, gcnt);
    int per = (N + 255) / 256;
    pool_reduce<<<64, 256, 0, stream>>>((const float*)H2b, batch, gsum, gmax, gcnt, N, per);
    classifier<<<NG, 128, 0, stream>>>(gsum, gmax, gcnt, Wc1, bc1, Wc2, bc2, (float*)d_out);
}

// Round 10
// 539.125 us; speedup vs baseline: 1.1993x; 1.1638x over previous
//
#include <hip/hip_runtime.h>
#include <math.h>

#define NG 64          // graphs
#define F_IN 128
#define NEG_SLOPE 0.2f

typedef __attribute__((ext_vector_type(8))) short s16x8;
typedef __attribute__((ext_vector_type(4))) float f32x4;

// ---------- helpers ----------
static __device__ __forceinline__ float elu_f(float x) { return x > 0.f ? x : expm1f(x); }
static __device__ __forceinline__ float lrelu(float x) { return x > 0.f ? x : NEG_SLOPE * x; }
static __device__ __forceinline__ unsigned enc_f32(float x) {
    unsigned u = __float_as_uint(x);
    return (u & 0x80000000u) ? ~u : (u | 0x80000000u);
}
static __device__ __forceinline__ float dec_f32(unsigned u) {
    unsigned b = (u & 0x80000000u) ? (u & 0x7fffffffu) : ~u;
    return __uint_as_float(b);
}
static __device__ __forceinline__ unsigned short bf16_rn(float x) {
    unsigned u = __float_as_uint(x);
    unsigned r = u + 0x7FFFu + ((u >> 16) & 1u);
    return (unsigned short)(r >> 16);
}
static __device__ __forceinline__ float bf16_to_f32(unsigned short h) {
    return __uint_as_float(((unsigned)h) << 16);
}

// MFMA fragment-order layout: element (row,k) of a [R][K] bf16 matrix.
// 16-row x 32-k tile = 512 elems, lane-major -> one wave fragment = 1KB contiguous.
static __device__ __forceinline__ size_t fragaddr(int row, int k, int K) {
    return ((size_t)(row >> 4) * (K >> 5) + (k >> 5)) * 512
         + (size_t)(((k & 31) >> 3) * 128 + (row & 15) * 8 + (k & 7));
}

// ---------- pre-pack: f32 [R][K] -> frag-order hi/lo bf16 ----------
__global__ void convert_frag(const float* __restrict__ in, unsigned short* __restrict__ hi,
                             unsigned short* __restrict__ lo, int R, int K) {
    int t = blockIdx.x * blockDim.x + threadIdx.x;
    if (t * 8 >= R * K) return;
    int row = (t * 8) / K;
    int k0 = (t * 8) % K;
    float4 v0 = *(const float4*)&in[(size_t)row * K + k0];
    float4 v1 = *(const float4*)&in[(size_t)row * K + k0 + 4];
    float v[8] = {v0.x, v0.y, v0.z, v0.w, v1.x, v1.y, v1.z, v1.w};
    unsigned short h[8], l[8];
    #pragma unroll
    for (int i = 0; i < 8; ++i) {
        h[i] = bf16_rn(v[i]);
        l[i] = bf16_rn(v[i] - bf16_to_f32(h[i]));
    }
    size_t a = fragaddr(row, k0, K);
    *(ushort4*)&hi[a]     = make_ushort4(h[0], h[1], h[2], h[3]);
    *(ushort4*)&hi[a + 4] = make_ushort4(h[4], h[5], h[6], h[7]);
    *(ushort4*)&lo[a]     = make_ushort4(l[0], l[1], l[2], l[3]);
    *(ushort4*)&lo[a + 4] = make_ushort4(l[4], l[5], l[6], l[7]);
}

// u[h][i] = sum_o W1[h*64+o][i] * a[h][o]   (layer-1 commute attention scalars)
__global__ void uvec_kernel(const float* __restrict__ W1, const float* __restrict__ a1s,
                            const float* __restrict__ a1d,
                            float* __restrict__ us, float* __restrict__ ud) {
    int h = threadIdx.x >> 6;
    int i = threadIdx.x & 63;
    float s = 0.f, d = 0.f;
    for (int o = 0; o < 64; ++o) {
        float w = W1[(h * 64 + o) * 64 + i];
        s = fmaf(w, a1s[h * 64 + o], s);
        d = fmaf(w, a1d[h * 64 + o], d);
    }
    us[h * 64 + i] = s;
    ud[h * 64 + i] = d;
}

// ---------- CSR build ----------
__global__ void hist_kernel(const int* __restrict__ ei, int* __restrict__ cnt, int E, int N) {
    int e = blockIdx.x * blockDim.x + threadIdx.x;
    int ET = E + N;
    if (e >= ET) return;
    int dst = (e < E) ? ei[E + e] : (e - E);
    atomicAdd(&cnt[dst], 1);
}

__global__ void scan1_kernel(const int* __restrict__ cnt, int* __restrict__ excl,
                             int* __restrict__ bsum, int n) {
    __shared__ int sm[256];
    int t = threadIdx.x;
    int base = blockIdx.x * 1024 + t * 4;
    int v[4];
    #pragma unroll
    for (int u = 0; u < 4; ++u) { int idx = base + u; v[u] = (idx < n) ? cnt[idx] : 0; }
    int tsum = v[0] + v[1] + v[2] + v[3];
    sm[t] = tsum;
    __syncthreads();
    for (int off = 1; off < 256; off <<= 1) {
        int y = (t >= off) ? sm[t - off] : 0;
        __syncthreads();
        sm[t] += y;
        __syncthreads();
    }
    int run = sm[t] - tsum;
    #pragma unroll
    for (int u = 0; u < 4; ++u) {
        int idx = base + u;
        if (idx < n) excl[idx] = run;
        run += v[u];
    }
    if (t == 255) bsum[blockIdx.x] = sm[255];
}

__global__ void scan2_kernel(int* __restrict__ bsum, int* __restrict__ offs, int nb, int n) {
    if (blockIdx.x == 0 && threadIdx.x == 0) {
        int run = 0;
        for (int b = 0; b < nb; ++b) { int t = bsum[b]; bsum[b] = run; run += t; }
        offs[n] = run;
    }
}

__global__ void scan3_kernel(int* __restrict__ offs, const int* __restrict__ bsum, int n) {
    int base = blockIdx.x * 1024 + threadIdx.x * 4;
    int add = bsum[blockIdx.x];
    #pragma unroll
    for (int u = 0; u < 4; ++u) { int idx = base + u; if (idx < n) offs[idx] += add; }
}

__global__ void scatter_kernel(const int* __restrict__ ei, const int* __restrict__ offs,
                               int* __restrict__ cursor, int* __restrict__ csr_src, int E, int N) {
    int e = blockIdx.x * blockDim.x + threadIdx.x;
    int ET = E + N;
    if (e >= ET) return;
    int src, dst;
    if (e < E) { src = ei[e]; dst = ei[E + e]; }
    else       { src = e - E; dst = e - E; }
    int pos = offs[dst] + atomicAdd(&cursor[dst], 1);
    csr_src[pos] = src;
}

// ---------- frag-order LDS-free split-bf16 MFMA GEMM ----------
// A, W in frag-order hi/lo ushort arrays. All loads are 16B/lane coalesced.
// BN==256: block = 64 rows x 256 cols; 4 waves split cols (cbase=w*64), RF=4 rows.
// BN==64:  block = 128 rows x 64 cols; 4 waves split rows (rbase=w*32), RF=2.
// OUTM: 0=f32 row-major, 1=bf16 row-major, 3=frag-order split (Ohi/Olo).
template<int K, int AK, int BN, int HATT, bool SHARED, bool SLICED, bool DO_ELU, int OUTM>
__global__ __launch_bounds__(256) void gemm_frag(const unsigned short* __restrict__ Ahi,
                                                 const unsigned short* __restrict__ Alo,
                                                 const unsigned short* __restrict__ Whi,
                                                 const unsigned short* __restrict__ Wlo,
                                                 void* __restrict__ OutV,
                                                 unsigned short* __restrict__ Ohi,
                                                 unsigned short* __restrict__ Olo,
                                                 int M,
                                                 const float* __restrict__ bias,
                                                 const float* __restrict__ asrc,
                                                 const float* __restrict__ adst,
                                                 float* __restrict__ S, float* __restrict__ D,
                                                 int N) {
    constexpr int RF = (BN == 256) ? 4 : 2;
    const int t = threadIdx.x;
    const int lane = t & 63;
    const int w = t >> 6;
    const int lj = lane & 15;
    const int kg = lane >> 4;
    const int n0 = blockIdx.x * ((BN == 256) ? 64 : 128);
    const int m0 = blockIdx.y * BN;
    const int rbase = (BN == 256) ? 0 : w * 32;
    const int cbase = (BN == 256) ? w * 64 : 0;
    const int aoff = SLICED ? blockIdx.y * K : 0;
    const unsigned short* __restrict__ WhiB = SLICED ? Whi + (size_t)blockIdx.y * BN * K : Whi;
    const unsigned short* __restrict__ WloB = SLICED ? Wlo + (size_t)blockIdx.y * BN * K : Wlo;

    f32x4 acc[RF][4];
    #pragma unroll
    for (int rf = 0; rf < RF; ++rf)
        #pragma unroll
        for (int cf = 0; cf < 4; ++cf) acc[rf][cf] = (f32x4){0.f, 0.f, 0.f, 0.f};

    for (int kc = 0; kc < K; kc += 32) {
        s16x8 ah[RF], al[RF];
        #pragma unroll
        for (int rf = 0; rf < RF; ++rf) {
            size_t a = fragaddr(n0 + rbase + rf * 16 + lj, aoff + kc + kg * 8, AK);
            ah[rf] = *(const s16x8*)&Ahi[a];
            al[rf] = *(const s16x8*)&Alo[a];
        }
        #pragma unroll
        for (int cf = 0; cf < 4; ++cf) {
            int bcol = (SLICED ? 0 : m0) + cbase + cf * 16 + lj;
            size_t b = fragaddr(bcol, kc + kg * 8, K);
            s16x8 bh = *(const s16x8*)&WhiB[b];
            s16x8 bl = *(const s16x8*)&WloB[b];
            #pragma unroll
            for (int rf = 0; rf < RF; ++rf) {
                acc[rf][cf] = __builtin_amdgcn_mfma_f32_16x16x32_bf16(ah[rf], bh, acc[rf][cf], 0, 0, 0);
                acc[rf][cf] = __builtin_amdgcn_mfma_f32_16x16x32_bf16(ah[rf], bl, acc[rf][cf], 0, 0, 0);
                acc[rf][cf] = __builtin_amdgcn_mfma_f32_16x16x32_bf16(al[rf], bh, acc[rf][cf], 0, 0, 0);
            }
        }
    }

    // epilogue: C/D layout col=lane&15, row=(lane>>4)*4+reg
    #pragma unroll
    for (int cf = 0; cf < 4; ++cf) {
        int gcol = m0 + cbase + cf * 16 + lj;
        float bv = bias ? bias[gcol] : 0.f;
        #pragma unroll
        for (int rf = 0; rf < RF; ++rf) {
            #pragma unroll
            for (int r = 0; r < 4; ++r) {
                int gn = n0 + rbase + rf * 16 + (lane >> 4) * 4 + r;
                if (gn < N) {
                    float o = acc[rf][cf][r] + bv;
                    if (DO_ELU) o = elu_f(o);
                    if (OUTM == 0) {
                        ((float*)OutV)[(size_t)gn * M + gcol] = o;
                    } else if (OUTM == 1) {
                        ((unsigned short*)OutV)[(size_t)gn * M + gcol] = bf16_rn(o);
                    } else {
                        unsigned short hv = bf16_rn(o);
                        unsigned short lv = bf16_rn(o - bf16_to_f32(hv));
                        size_t a2 = fragaddr(gn, gcol, M);
                        Ohi[a2] = hv; Olo[a2] = lv;
                    }
                }
            }
        }
    }
    // fused attention scalars (f32 acc, post-bias)
    if (HATT > 0) {
        const int HS = SHARED ? HATT : 1;
        #pragma unroll
        for (int hh = 0; hh < HS; ++hh) {
            const int head = SHARED ? hh : w;
            float aw[4], dw[4], bw[4];
            #pragma unroll
            for (int c2 = 0; c2 < 4; ++c2) {
                aw[c2] = asrc[head * 64 + c2 * 16 + lj];
                dw[c2] = adst[head * 64 + c2 * 16 + lj];
                bw[c2] = bias ? bias[m0 + cbase + c2 * 16 + lj] : 0.f;
            }
            #pragma unroll
            for (int rf = 0; rf < RF; ++rf) {
                #pragma unroll
                for (int r = 0; r < 4; ++r) {
                    float sp = 0.f, dp = 0.f;
                    #pragma unroll
                    for (int c2 = 0; c2 < 4; ++c2) {
                        float vv = acc[rf][c2][r] + bw[c2];
                        sp = fmaf(vv, aw[c2], sp);
                        dp = fmaf(vv, dw[c2], dp);
                    }
                    #pragma unroll
                    for (int off = 1; off < 16; off <<= 1) {
                        sp += __shfl_xor(sp, off);
                        dp += __shfl_xor(dp, off);
                    }
                    if (lj == 0) {
                        int gn = n0 + rbase + rf * 16 + (lane >> 4) * 4 + r;
                        if (gn < N) { S[gn * HATT + head] = sp; D[gn * HATT + head] = dp; }
                    }
                }
            }
        }
    }
}

// ---------- layer-1 aggregation over raw emb (commuted); outputs frag-order split ----------
__global__ __launch_bounds__(256, 8) void gat_agg_x(const float* __restrict__ xA,  // [N][64] f32
                                                    const float* __restrict__ s,   // [N][4]
                                                    const float* __restrict__ d,
                                                    const int* __restrict__ offs,
                                                    const int* __restrict__ csr_src,
                                                    unsigned short* __restrict__ Gh,
                                                    unsigned short* __restrict__ Gl,
                                                    int N) {
    __shared__ float stash[4][64 * 5];
    int wv = threadIdx.x >> 6;
    int lane = threadIdx.x & 63;
    int node = (blockIdx.x * blockDim.x + threadIdx.x) >> 6;
    if (node >= N) return;
    float* st = stash[wv];
    int e0 = offs[node], e1 = offs[node + 1];
    float4 dv4 = *(const float4*)&d[node * 4];
    float dd[4] = {dv4.x, dv4.y, dv4.z, dv4.w};
    float mrun[4] = {-INFINITY, -INFINITY, -INFINITY, -INFINITY};
    float den[4] = {0.f, 0.f, 0.f, 0.f};
    float acc[4] = {0.f, 0.f, 0.f, 0.f};

    for (int base = e0; base < e1; base += 64) {
        int cnt = min(64, e1 - base);
        float ev[4] = {-INFINITY, -INFINITY, -INFINITY, -INFINITY};
        if (lane < cnt) {
            int src = csr_src[base + lane];
            float4 sv = *(const float4*)&s[src * 4];
            ev[0] = lrelu(sv.x + dd[0]); ev[1] = lrelu(sv.y + dd[1]);
            ev[2] = lrelu(sv.z + dd[2]); ev[3] = lrelu(sv.w + dd[3]);
            st[lane * 5 + 0] = ev[0]; st[lane * 5 + 1] = ev[1];
            st[lane * 5 + 2] = ev[2]; st[lane * 5 + 3] = ev[3];
            st[lane * 5 + 4] = __int_as_float(src);
        }
        #pragma unroll
        for (int h = 0; h < 4; ++h) {
            float m = ev[h];
            #pragma unroll
            for (int off = 32; off; off >>= 1) m = fmaxf(m, __shfl_xor(m, off));
            float mnew = fmaxf(mrun[h], m);
            float scale = __expf(mrun[h] - mnew);
            acc[h] *= scale; den[h] *= scale;
            mrun[h] = mnew;
        }
        int k = 0;
        for (; k + 4 <= cnt; k += 4) {
            int si[4];
            #pragma unroll
            for (int u = 0; u < 4; ++u) si[u] = __float_as_int(st[(k + u) * 5 + 4]);
            float vx[4];
            #pragma unroll
            for (int u = 0; u < 4; ++u) vx[u] = xA[(size_t)si[u] * 64 + lane];
            #pragma unroll
            for (int u = 0; u < 4; ++u) {
                #pragma unroll
                for (int h = 0; h < 4; ++h) {
                    float p = __expf(st[(k + u) * 5 + h] - mrun[h]);
                    den[h] += p;
                    acc[h] = fmaf(p, vx[u], acc[h]);
                }
            }
        }
        for (; k < cnt; ++k) {
            int src = __float_as_int(st[k * 5 + 4]);
            float v = xA[(size_t)src * 64 + lane];
            #pragma unroll
            for (int h = 0; h < 4; ++h) {
                float p = __expf(st[k * 5 + h] - mrun[h]);
                den[h] += p;
                acc[h] = fmaf(p, v, acc[h]);
            }
        }
    }
    #pragma unroll
    for (int h = 0; h < 4; ++h) {
        float v = acc[h] / (den[h] + 1e-16f);
        unsigned short hv = bf16_rn(v);
        unsigned short lv = bf16_rn(v - bf16_to_f32(hv));
        size_t a = fragaddr(node, h * 64 + lane, 256);
        Gh[a] = hv; Gl[a] = lv;
    }
}

// ---------- GAT aggregation: one wave per dst node, chunked online softmax ----------
// Gathers bf16 row-major table. H=4+FRAGOUT: write frag-order split; H=1: f32 row-major.
template<int H, bool FRAGOUT>
__global__ __launch_bounds__(256, 8) void gat_agg(const unsigned short* __restrict__ hp,
                                                  const float* __restrict__ s,
                                                  const float* __restrict__ d,
                                                  const int* __restrict__ offs,
                                                  const int* __restrict__ csr_src,
                                                  const float* __restrict__ bias,
                                                  float* __restrict__ outF,
                                                  unsigned short* __restrict__ outHi,
                                                  unsigned short* __restrict__ outLo,
                                                  int N) {
    const int SW = (H == 4) ? 5 : 2;
    __shared__ float stash[4][64 * 5];
    int wv = threadIdx.x >> 6;
    int lane = threadIdx.x & 63;
    int node = (blockIdx.x * blockDim.x + threadIdx.x) >> 6;
    if (node >= N) return;
    float* st = stash[wv];
    int e0 = offs[node], e1 = offs[node + 1];

    float dd[H];
    #pragma unroll
    for (int h = 0; h < H; ++h) dd[h] = d[node * H + h];

    const int hd = (H == 4) ? (lane >> 4) : 0;

    float mrun = -INFINITY;
    float acc0 = 0.f, acc1 = 0.f, acc2 = 0.f, acc3 = 0.f, den = 0.f;

    for (int base = e0; base < e1; base += 64) {
        int cnt = min(64, e1 - base);
        float ev[H];
        #pragma unroll
        for (int h = 0; h < H; ++h) ev[h] = -INFINITY;
        if (lane < cnt) {
            int src = csr_src[base + lane];
            if (H == 4) {
                float4 sv = *(const float4*)&s[src * 4];
                ev[0] = lrelu(sv.x + dd[0]); ev[1] = lrelu(sv.y + dd[1]);
                ev[2] = lrelu(sv.z + dd[2]); ev[3] = lrelu(sv.w + dd[3]);
                st[lane * 5 + 0] = ev[0]; st[lane * 5 + 1] = ev[1];
                st[lane * 5 + 2] = ev[2]; st[lane * 5 + 3] = ev[3];
                st[lane * 5 + 4] = __int_as_float(src);
            } else {
                ev[0] = lrelu(s[src] + dd[0]);
                st[lane * 2 + 0] = ev[0];
                st[lane * 2 + 1] = __int_as_float(src);
            }
        }
        float mc[H];
        #pragma unroll
        for (int h = 0; h < H; ++h) {
            float m = ev[h];
            #pragma unroll
            for (int off = 32; off; off >>= 1) m = fmaxf(m, __shfl_xor(m, off));
            mc[h] = m;
        }
        float mch = mc[0];
        if (H == 4)
            mch = (lane & 32) ? ((lane & 16) ? mc[3] : mc[2]) : ((lane & 16) ? mc[1] : mc[0]);
        float mnew = fmaxf(mrun, mch);
        float scale = __expf(mrun - mnew);
        acc0 *= scale; acc1 *= scale; acc2 *= scale; acc3 *= scale; den *= scale;
        mrun = mnew;

        int k = 0;
        for (; k + 4 <= cnt; k += 4) {
            float ea = st[(k + 0) * SW + hd];
            float eb = st[(k + 1) * SW + hd];
            float ec = st[(k + 2) * SW + hd];
            float ed = st[(k + 3) * SW + hd];
            int sa = __float_as_int(st[(k + 0) * SW + SW - 1]);
            int sb = __float_as_int(st[(k + 1) * SW + SW - 1]);
            int sc = __float_as_int(st[(k + 2) * SW + SW - 1]);
            int sd_ = __float_as_int(st[(k + 3) * SW + SW - 1]);
            float pa = __expf(ea - mrun);
            float pb = __expf(eb - mrun);
            float pc = __expf(ec - mrun);
            float pd = __expf(ed - mrun);
            den += (pa + pb) + (pc + pd);
            if (H == 4) {
                uint2 ua = *(const uint2*)&hp[(size_t)sa * 256 + lane * 4];
                uint2 ub = *(const uint2*)&hp[(size_t)sb * 256 + lane * 4];
                uint2 uc = *(const uint2*)&hp[(size_t)sc * 256 + lane * 4];
                uint2 ud = *(const uint2*)&hp[(size_t)sd_ * 256 + lane * 4];
                acc0 = fmaf(pa, __uint_as_float((ua.x & 0xffffu) << 16), acc0);
                acc1 = fmaf(pa, __uint_as_float(ua.x & 0xffff0000u), acc1);
                acc2 = fmaf(pa, __uint_as_float((ua.y & 0xffffu) << 16), acc2);
                acc3 = fmaf(pa, __uint_as_float(ua.y & 0xffff0000u), acc3);
                acc0 = fmaf(pb, __uint_as_float((ub.x & 0xffffu) << 16), acc0);
                acc1 = fmaf(pb, __uint_as_float(ub.x & 0xffff0000u), acc1);
                acc2 = fmaf(pb, __uint_as_float((ub.y & 0xffffu) << 16), acc2);
                acc3 = fmaf(pb, __uint_as_float(ub.y & 0xffff0000u), acc3);
                acc0 = fmaf(pc, __uint_as_float((uc.x & 0xffffu) << 16), acc0);
                acc1 = fmaf(pc, __uint_as_float(uc.x & 0xffff0000u), acc1);
                acc2 = fmaf(pc, __uint_as_float((uc.y & 0xffffu) << 16), acc2);
                acc3 = fmaf(pc, __uint_as_float(uc.y & 0xffff0000u), acc3);
                acc0 = fmaf(pd, __uint_as_float((ud.x & 0xffffu) << 16), acc0);
                acc1 = fmaf(pd, __uint_as_float(ud.x & 0xffff0000u), acc1);
                acc2 = fmaf(pd, __uint_as_float((ud.y & 0xffffu) << 16), acc2);
                acc3 = fmaf(pd, __uint_as_float(ud.y & 0xffff0000u), acc3);
            } else {
                float ha = bf16_to_f32(hp[(size_t)sa * 64 + lane]);
                float hb = bf16_to_f32(hp[(size_t)sb * 64 + lane]);
                float hc = bf16_to_f32(hp[(size_t)sc * 64 + lane]);
                float hdv = bf16_to_f32(hp[(size_t)sd_ * 64 + lane]);
                acc0 = fmaf(pa, ha, acc0);
                acc0 = fmaf(pb, hb, acc0);
                acc0 = fmaf(pc, hc, acc0);
                acc0 = fmaf(pd, hdv, acc0);
            }
        }
        for (; k < cnt; ++k) {
            float e = st[k * SW + hd];
            int src = __float_as_int(st[k * SW + SW - 1]);
            float p = __expf(e - mrun);
            den += p;
            if (H == 4) {
                uint2 uv = *(const uint2*)&hp[(size_t)src * 256 + lane * 4];
                acc0 = fmaf(p, __uint_as_float((uv.x & 0xffffu) << 16), acc0);
                acc1 = fmaf(p, __uint_as_float(uv.x & 0xffff0000u), acc1);
                acc2 = fmaf(p, __uint_as_float((uv.y & 0xffffu) << 16), acc2);
                acc3 = fmaf(p, __uint_as_float(uv.y & 0xffff0000u), acc3);
            } else {
                acc0 = fmaf(p, bf16_to_f32(hp[(size_t)src * 64 + lane]), acc0);
            }
        }
    }

    float inv = 1.0f / (den + 1e-16f);
    if (H == 4) {
        float4 bv = *(const float4*)&bias[lane * 4];
        float o0 = elu_f(acc0 * inv + bv.x);
        float o1 = elu_f(acc1 * inv + bv.y);
        float o2 = elu_f(acc2 * inv + bv.z);
        float o3 = elu_f(acc3 * inv + bv.w);
        if (FRAGOUT) {
            unsigned short h0 = bf16_rn(o0), h1 = bf16_rn(o1), h2 = bf16_rn(o2), h3 = bf16_rn(o3);
            ushort4 hq = make_ushort4(h0, h1, h2, h3);
            ushort4 lq = make_ushort4(bf16_rn(o0 - bf16_to_f32(h0)),
                                      bf16_rn(o1 - bf16_to_f32(h1)),
                                      bf16_rn(o2 - bf16_to_f32(h2)),
                                      bf16_rn(o3 - bf16_to_f32(h3)));
            size_t a = fragaddr(node, lane * 4, 256);
            *(ushort4*)&outHi[a] = hq;
            *(ushort4*)&outLo[a] = lq;
        } else {
            float4 o = make_float4(o0, o1, o2, o3);
            *(float4*)&outF[(size_t)node * 256 + lane * 4] = o;
        }
    } else {
        outF[(size_t)node * 64 + lane] = elu_f(acc0 * inv + bias[lane]);
    }
}

// ---------- pooling ----------
__global__ void pool_init(float* gsum, unsigned* gmax, int* gcnt) {
    int t = blockIdx.x * blockDim.x + threadIdx.x;
    if (t < NG * 64) { gsum[t] = 0.f; gmax[t] = enc_f32(-INFINITY); }
    if (t < NG) gcnt[t] = 0;
}

__global__ void pool_reduce(const float* __restrict__ h3, const int* __restrict__ batch,
                            float* __restrict__ gsum, unsigned* __restrict__ gmax,
                            int* __restrict__ gcnt, int N, int per) {
    int w = (blockIdx.x * blockDim.x + threadIdx.x) >> 6;
    int lane = threadIdx.x & 63;
    int n0 = w * per;
    int n1 = min(N, n0 + per);
    float lsum = 0.f, lmax = -INFINITY;
    int cur = -1, cnt = 0;
    for (int n = n0; n < n1; ++n) {
        int g = batch[n];
        if (g != cur) {
            if (cur >= 0) {
                atomicAdd(&gsum[cur * 64 + lane], lsum);
                atomicMax(&gmax[cur * 64 + lane], enc_f32(lmax));
                if (lane == 0) atomicAdd(&gcnt[cur], cnt);
            }
            cur = g; lsum = 0.f; lmax = -INFINITY; cnt = 0;
        }
        float v = h3[(size_t)n * 64 + lane];
        lsum += v; lmax = fmaxf(lmax, v); cnt++;
    }
    if (cur >= 0) {
        atomicAdd(&gsum[cur * 64 + lane], lsum);
        atomicMax(&gmax[cur * 64 + lane], enc_f32(lmax));
        if (lane == 0) atomicAdd(&gcnt[cur], cnt);
    }
}

// ---------- classifier: one block per graph ----------
__global__ __launch_bounds__(128) void classifier(const float* __restrict__ gsum,
                                                  const unsigned* __restrict__ gmax,
                                                  const int* __restrict__ gcnt,
                                                  const float* __restrict__ Wc1,
                                                  const float* __restrict__ bc1,
                                                  const float* __restrict__ Wc2,
                                                  const float* __restrict__ bc2,
                                                  float* __restrict__ out) {
    __shared__ float gv[128];
    __shared__ float z1[64];
    int g = blockIdx.x, t = threadIdx.x;
    int cnt = gcnt[g];
    if (t < 64) {
        gv[t] = gsum[g * 64 + t] / fmaxf((float)cnt, 1.f);
    } else {
        float mx = dec_f32(gmax[g * 64 + (t - 64)]);
        gv[t] = (cnt > 0) ? mx : 0.f;
    }
    __syncthreads();
    if (t < 64) {
        float a = bc1[t];
        for (int k = 0; k < 128; ++k) a = fmaf(Wc1[t * 128 + k], gv[k], a);
        z1[t] = a > 0.f ? a : 0.f;
    }
    __syncthreads();
    if (t < 10) {
        float a = bc2[t];
        for (int k = 0; k < 64; ++k) a = fmaf(Wc2[t * 64 + k], z1[k], a);
        out[g * 10 + t] = a;
    }
}

// ---------- launch ----------
extern "C" void kernel_launch(void* const* d_in, const int* in_sizes, int n_in,
                              void* d_out, int out_size, void* d_ws, size_t ws_size,
                              hipStream_t stream) {
    const float* x      = (const float*)d_in[0];
    const int*   ei     = (const int*)d_in[1];
    const int*   batch  = (const int*)d_in[2];
    const float* W_emb  = (const float*)d_in[3];
    const float* b_emb  = (const float*)d_in[4];
    const float* W1     = (const float*)d_in[5];
    const float* as1    = (const float*)d_in[6];
    const float* ad1    = (const float*)d_in[7];
    const float* b1     = (const float*)d_in[8];
    const float* W2     = (const float*)d_in[9];
    const float* as2    = (const float*)d_in[10];
    const float* ad2    = (const float*)d_in[11];
    const float* b2     = (const float*)d_in[12];
    const float* W3     = (const float*)d_in[13];
    const float* as3    = (const float*)d_in[14];
    const float* ad3    = (const float*)d_in[15];
    const float* b3     = (const float*)d_in[16];
    const float* Wc1    = (const float*)d_in[17];
    const float* bc1    = (const float*)d_in[18];
    const float* Wc2    = (const float*)d_in[19];
    const float* bc2    = (const float*)d_in[20];

    const int N = in_sizes[0] / F_IN;   // 50000
    const int E = in_sizes[1] / 2;      // 800000
    const int ET = E + N;
    const int GB64 = (N + 63) / 64;     // 782  (BN=256 gemm, 64-row blocks)
    const int GB128 = (N + 127) / 128;  // 391  (BN=64 gemms, 128-row blocks)
    const int ROWS_FR = ((N + 255) / 256) * 256;  // 50176 alloc granularity
    const size_t FR128 = (size_t)(ROWS_FR / 16) * (128 / 32) * 512;
    const size_t FR256 = (size_t)(ROWS_FR / 16) * (256 / 32) * 512;

    // workspace carve-up (256B aligned)
    size_t off = 0;
    auto alloc = [&](size_t bytes) -> void* {
        void* p = (char*)d_ws + off;
        off += (bytes + 255) & ~(size_t)255;
        return p;
    };
    unsigned short* Xh  = (unsigned short*)alloc(FR128 * 2);
    unsigned short* Xl  = (unsigned short*)alloc(FR128 * 2);
    float*          Aemb= (float*)alloc((size_t)N * 64 * 4);    // emb f32; later H3b (bf16)
    unsigned short* Gh  = (unsigned short*)alloc(FR256 * 2);    // G frag; later C2 frag
    unsigned short* Gl  = (unsigned short*)alloc(FR256 * 2);
    unsigned short* C1h = (unsigned short*)alloc(FR256 * 2);
    unsigned short* C1l = (unsigned short*)alloc(FR256 * 2);
    unsigned short* H2b = (unsigned short*)alloc((size_t)N * 256 * 2);  // h2 bf16; later h3 f32
    unsigned short* WhE = (unsigned short*)alloc(64 * 128 * 2);
    unsigned short* WlE = (unsigned short*)alloc(64 * 128 * 2);
    unsigned short* Wh1 = (unsigned short*)alloc(256 * 64 * 2);
    unsigned short* Wl1 = (unsigned short*)alloc(256 * 64 * 2);
    unsigned short* Wh2 = (unsigned short*)alloc(256 * 256 * 2);
    unsigned short* Wl2 = (unsigned short*)alloc(256 * 256 * 2);
    unsigned short* Wh3 = (unsigned short*)alloc(64 * 256 * 2);
    unsigned short* Wl3 = (unsigned short*)alloc(64 * 256 * 2);
    float*    us1     = (float*)alloc(4 * 64 * 4);
    float*    ud1     = (float*)alloc(4 * 64 * 4);
    float*    S       = (float*)alloc((size_t)N * 4 * 4);
    float*    D       = (float*)alloc((size_t)N * 4 * 4);
    int*      offs    = (int*)alloc((size_t)(N + 1) * 4);
    int*      cnt     = (int*)alloc((size_t)N * 4);
    int*      bsum    = (int*)alloc(64 * 4);
    int*      csr_src = (int*)alloc((size_t)ET * 4);
    float*    gsum    = (float*)alloc(NG * 64 * 4);
    unsigned* gmax    = (unsigned*)alloc(NG * 64 * 4);
    int*      gcnt    = (int*)alloc(NG * 4);
    (void)ws_size; (void)n_in; (void)out_size;

    const int SCB = (N + 1023) / 1024;

    // pre-pack to fragment order
    convert_frag<<<(N * 128 / 8 + 255) / 256, 256, 0, stream>>>(x, Xh, Xl, N, 128);
    convert_frag<<<4, 256, 0, stream>>>(W_emb, WhE, WlE, 64, 128);
    convert_frag<<<8, 256, 0, stream>>>(W1, Wh1, Wl1, 256, 64);
    convert_frag<<<32, 256, 0, stream>>>(W2, Wh2, Wl2, 256, 256);
    convert_frag<<<8, 256, 0, stream>>>(W3, Wh3, Wl3, 64, 256);
    uvec_kernel<<<1, 256, 0, stream>>>(W1, as1, ad1, us1, ud1);

    // CSR build
    hipMemsetAsync(cnt, 0, (size_t)N * 4, stream);
    hist_kernel<<<(ET + 255) / 256, 256, 0, stream>>>(ei, cnt, E, N);
    scan1_kernel<<<SCB, 256, 0, stream>>>(cnt, offs, bsum, N);
    scan2_kernel<<<1, 64, 0, stream>>>(bsum, offs, SCB, N);
    scan3_kernel<<<SCB, 256, 0, stream>>>(offs, bsum, N);
    hipMemsetAsync(cnt, 0, (size_t)N * 4, stream);
    scatter_kernel<<<(ET + 255) / 256, 256, 0, stream>>>(ei, offs, cnt, csr_src, E, N);

    const int NWV = (N * 64 + 255) / 256;

    // embedding: Aemb(f32) = x@W_embT + b_emb, fused s1,d1 via commute u-vectors
    gemm_frag<128, 128, 64, 4, true, false, false, 0><<<dim3(GB128, 1), 256, 0, stream>>>(
        Xh, Xl, WhE, WlE, Aemb, nullptr, nullptr, 64, b_emb, us1, ud1, S, D, N);
    // layer-1 commuted aggregation (gathers f32 emb; outputs frag G)
    gat_agg_x<<<NWV, 256, 0, stream>>>(Aemb, S, D, offs, csr_src, Gh, Gl, N);
    // per-head transform: C1 = frag(elu(G_h @ W1_hT + b1))
    gemm_frag<64, 256, 64, 0, false, true, true, 3><<<dim3(GB128, 4), 256, 0, stream>>>(
        Gh, Gl, Wh1, Wl1, nullptr, C1h, C1l, 256, b1, nullptr, nullptr, nullptr, nullptr, N);
    // layer 2: H2b(bf16) = C1@W2T, fused s2,d2
    gemm_frag<256, 256, 256, 4, false, false, false, 1><<<dim3(GB64, 1), 256, 0, stream>>>(
        C1h, C1l, Wh2, Wl2, H2b, nullptr, nullptr, 256, nullptr, as2, ad2, S, D, N);
    gat_agg<4, true><<<NWV, 256, 0, stream>>>(H2b, S, D, offs, csr_src, b2,
                                              nullptr, Gh, Gl, N);
    // layer 3: H3b(bf16, in Aemb buffer) = C2@W3T, fused s3,d3
    gemm_frag<256, 256, 64, 1, true, false, false, 1><<<dim3(GB128, 1), 256, 0, stream>>>(
        Gh, Gl, Wh3, Wl3, (unsigned short*)Aemb, nullptr, nullptr, 64, nullptr, as3, ad3, S, D, N);
    gat_agg<1, false><<<NWV, 256, 0, stream>>>((const unsigned short*)Aemb, S, D, offs, csr_src,
                                               b3, (float*)H2b, nullptr, nullptr, N);

    // pooling + classifier (h3 f32 in H2b buffer)
    pool_init<<<16, 256, 0, stream>>>(gsum, gmax, gcnt);
    const int PBLK = 512;                       // 2048 waves -> ~8 waves/CU
    int per = (N + PBLK * 4 - 1) / (PBLK * 4);  // nodes per wave
    pool_reduce<<<PBLK, 256, 0, stream>>>((const float*)H2b, batch, gsum, gmax, gcnt, N, per);
    classifier<<<NG, 128, 0, stream>>>(gsum, gmax, gcnt, Wc1, bc1, Wc2, bc2, (float*)d_out);
}